// Round 1
// baseline (658.681 us; speedup 1.0000x reference)
//
#include <hip/hip_runtime.h>

#define BB 32
#define SS 512
#define HH 256
#define MM (BB*SS)     // 16384 rows
#define MAXMEL 2048

// ---------------- conv1d (K=3, SAME, Cin=256 -> Cout=256) as GEMM ----------------
// M=16384, Kdim=768, N=256. Tile: TM=128 rows x TN=64 cols, 256 threads,
// per-thread 8 rows x 4 cols. A staged transposed in LDS (As[c][r]); B row-major.
#define TM 128
#define TN 64
#define KT 32
#define AST 130   // As row stride in floats (2-way bank aliasing only; 8B aligned)

__global__ __launch_bounds__(256) void conv_k3(
    const float* __restrict__ X,     // [MM, 256]
    const float* __restrict__ W,     // [768, 256]  (k*256+c, f)
    const float* __restrict__ bias,  // [256]
    float* __restrict__ Y)           // [MM, 256], ReLU applied
{
  __shared__ float As[KT][AST];
  __shared__ float Bs[KT][TN];
  const int bm = blockIdx.x;        // 0..127
  const int bn = blockIdx.y;        // 0..3
  const int b  = bm >> 2;           // 512/128 = 4 tiles per batch row
  const int s0 = (bm & 3) * TM;
  const int t  = threadIdx.x;
  const int tx = t & 15, ty = t >> 4;
  const int f0 = bn * TN;

  float acc[8][4];
  #pragma unroll
  for (int i = 0; i < 8; ++i)
    #pragma unroll
    for (int j = 0; j < 4; ++j) acc[i][j] = 0.f;

  const float* Xb = X + (size_t)b * SS * HH;

  for (int k = 0; k < 3; ++k) {
    for (int cb = 0; cb < HH; cb += KT) {
      __syncthreads();
      // stage A transposed: As[c][r], c in [0,32), r in [0,128)
      {
        const int c4 = (t & 7) * 4;
        const int r0 = t >> 3;          // 0..31
        #pragma unroll
        for (int i = 0; i < 4; ++i) {
          int r = r0 + 32 * i;
          int s = s0 + r + k - 1;
          float4 v = make_float4(0.f, 0.f, 0.f, 0.f);
          if (s >= 0 && s < SS)
            v = *(const float4*)(Xb + (size_t)s * HH + cb + c4);
          As[c4 + 0][r] = v.x;
          As[c4 + 1][r] = v.y;
          As[c4 + 2][r] = v.z;
          As[c4 + 3][r] = v.w;
        }
      }
      // stage B: Bs[rr][f4], 32 x 64
      {
        const int f4  = (t & 15) * 4;
        const int rr0 = t >> 4;         // 0..15
        #pragma unroll
        for (int i = 0; i < 2; ++i) {
          int rr = rr0 + 16 * i;
          const float* wp = W + (size_t)(k * HH + cb + rr) * HH + f0 + f4;
          *(float4*)&Bs[rr][f4] = *(const float4*)wp;
        }
      }
      __syncthreads();
      #pragma unroll
      for (int kk = 0; kk < KT; ++kk) {
        float a[8], bv[4];
        #pragma unroll
        for (int m = 0; m < 4; ++m) {
          float2 p = *(const float2*)&As[kk][ty * 8 + 2 * m];
          a[2 * m] = p.x; a[2 * m + 1] = p.y;
        }
        float4 bq = *(const float4*)&Bs[kk][tx * 4];
        bv[0] = bq.x; bv[1] = bq.y; bv[2] = bq.z; bv[3] = bq.w;
        #pragma unroll
        for (int i = 0; i < 8; ++i)
          #pragma unroll
          for (int j = 0; j < 4; ++j)
            acc[i][j] = fmaf(a[i], bv[j], acc[i][j]);
      }
    }
  }
  // epilogue: +bias, ReLU, store
  float4 bb4 = *(const float4*)(bias + f0 + tx * 4);
  #pragma unroll
  for (int i = 0; i < 8; ++i) {
    int r = ty * 8 + i;
    size_t row = (size_t)b * SS + s0 + r;
    float4 o;
    o.x = fmaxf(acc[i][0] + bb4.x, 0.f);
    o.y = fmaxf(acc[i][1] + bb4.y, 0.f);
    o.z = fmaxf(acc[i][2] + bb4.z, 0.f);
    o.w = fmaxf(acc[i][3] + bb4.w, 0.f);
    *(float4*)(Y + row * HH + f0 + tx * 4) = o;
  }
}

// ---------------- LayerNorm over channel dim (256), in-place ----------------
__global__ __launch_bounds__(256) void ln256(
    float* __restrict__ Y, const float* __restrict__ g, const float* __restrict__ be)
{
  int row  = blockIdx.x * 4 + (threadIdx.x >> 6);
  int lane = threadIdx.x & 63;
  float* p = Y + (size_t)row * HH + lane * 4;
  float4 v = *(float4*)p;
  float s = v.x + v.y + v.z + v.w;
  float q = v.x * v.x + v.y * v.y + v.z * v.z + v.w * v.w;
  #pragma unroll
  for (int d = 32; d > 0; d >>= 1) { s += __shfl_xor(s, d); q += __shfl_xor(q, d); }
  float mean = s * (1.f / 256.f);
  float var  = q * (1.f / 256.f) - mean * mean;
  float inv  = 1.0f / sqrtf(var + 1e-5f);
  float4 gg = *(const float4*)(g + lane * 4);
  float4 bb = *(const float4*)(be + lane * 4);
  v.x = (v.x - mean) * inv * gg.x + bb.x;
  v.y = (v.y - mean) * inv * gg.y + bb.y;
  v.z = (v.z - mean) * inv * gg.z + bb.z;
  v.w = (v.w - mean) * inv * gg.w + bb.w;
  *(float4*)p = v;
}

// ---------------- linear head: h@wl + bl, mask, *ctrl; dual write ----------------
__global__ __launch_bounds__(256) void linear_head(
    const float* __restrict__ Hb, const float* __restrict__ wl,
    const float* __restrict__ bl, const unsigned char* __restrict__ mask,
    const float* __restrict__ ctrl,   // may be null => 1.0
    float* __restrict__ out_a, float* __restrict__ out_b)
{
  int row  = blockIdx.x * 4 + (threadIdx.x >> 6);
  int lane = threadIdx.x & 63;
  float4 h = *(const float4*)(Hb + (size_t)row * HH + lane * 4);
  float4 w = *(const float4*)(wl + lane * 4);
  float s = h.x * w.x + h.y * w.y + h.z * w.z + h.w * w.w;
  #pragma unroll
  for (int d = 32; d > 0; d >>= 1) s += __shfl_xor(s, d);
  if (lane == 0) {
    float v = s + bl[0];
    if (mask[row]) v = 0.f;
    if (ctrl) v *= ctrl[0];
    out_a[row] = v;
    out_b[row] = v;
  }
}

// ---------------- bucketize(pred, bins) then x += emb[idx] ----------------
__global__ __launch_bounds__(256) void bucket_add(
    const float* __restrict__ Xin, const float* __restrict__ pred,
    const float* __restrict__ bins,   // [255]
    const float* __restrict__ emb,    // [256, 256]
    float* __restrict__ Xout)
{
  int row  = blockIdx.x * 4 + (threadIdx.x >> 6);
  int lane = threadIdx.x & 63;
  float v = pred[row];
  int lo = 0, hi = 255;                // searchsorted side='left'
  while (lo < hi) { int mid = (lo + hi) >> 1; if (bins[mid] < v) lo = mid + 1; else hi = mid; }
  float4 x = *(const float4*)(Xin + (size_t)row * HH + lane * 4);
  float4 e = *(const float4*)(emb + (size_t)lo * HH + lane * 4);
  x.x += e.x; x.y += e.y; x.z += e.z; x.w += e.w;
  *(float4*)(Xout + (size_t)row * HH + lane * 4) = x;
}

// ---------------- duration post: dur, cumsum, mel_len ----------------
__global__ __launch_bounds__(512) void dur_post(
    const float* __restrict__ logdur, const float* __restrict__ dc,
    float* __restrict__ out_dur, float* __restrict__ out_mel_len,
    int* __restrict__ cum_ws, int* __restrict__ mel_len_ws)
{
  __shared__ int wsum[8];
  int b = blockIdx.x, t = threadIdx.x;
  float ld = logdur[b * SS + t];
  float d  = fmaxf(rintf(expf(ld) - 1.f) * dc[0], 0.f);   // rintf = round half-to-even
  out_dur[b * SS + t] = d;
  int di = (int)d;                                        // trunc toward zero (d>=0)
  int lane = t & 63, w = t >> 6;
  int x = di;
  #pragma unroll
  for (int dd = 1; dd < 64; dd <<= 1) {
    int n = __shfl_up(x, dd);
    if (lane >= dd) x += n;
  }
  if (lane == 63) wsum[w] = x;
  __syncthreads();
  int off = 0;
  for (int i = 0; i < w; ++i) off += wsum[i];
  x += off;
  cum_ws[b * SS + t] = x;
  if (t == SS - 1) {
    int ml = min(x, MAXMEL);
    mel_len_ws[b] = ml;
    out_mel_len[b] = (float)ml;
  }
}

// ---------------- length regulator: gather + mask ----------------
__global__ __launch_bounds__(256) void gather_expand(
    const float* __restrict__ X2, const int* __restrict__ cum,
    const int* __restrict__ mel_len_ws,
    float* __restrict__ out_x, float* __restrict__ out_mask)
{
  __shared__ int c[SS];
  int b   = blockIdx.y;
  int tid = threadIdx.x;
  c[tid]       = cum[b * SS + tid];
  c[tid + 256] = cum[b * SS + tid + 256];
  __syncthreads();
  int w = tid >> 6, lane = tid & 63;
  int t = blockIdx.x * 4 + w;
  int lo = 0, hi = SS;                 // searchsorted side='right' over cum
  while (lo < hi) { int mid = (lo + hi) >> 1; if (c[mid] <= t) lo = mid + 1; else hi = mid; }
  int idx = min(lo, SS - 1);
  int ml  = mel_len_ws[b];
  bool m  = (t >= ml);
  float4 v = make_float4(0.f, 0.f, 0.f, 0.f);
  if (!m) v = *(const float4*)(X2 + ((size_t)b * SS + idx) * HH + lane * 4);
  *(float4*)(out_x + ((size_t)b * MAXMEL + t) * HH + lane * 4) = v;
  if (lane == 0) out_mask[b * MAXMEL + t] = m ? 1.f : 0.f;
}

// ---------------- launcher ----------------
extern "C" void kernel_launch(void* const* d_in, const int* in_sizes, int n_in,
                              void* d_out, int out_size, void* d_ws, size_t ws_size,
                              hipStream_t stream) {
  const float* x     = (const float*)d_in[0];
  const unsigned char* smask = (const unsigned char*)d_in[1];
  const float* pc    = (const float*)d_in[2];
  const float* ec    = (const float*)d_in[3];
  const float* dc    = (const float*)d_in[4];
  const float* pbins = (const float*)d_in[5];
  const float* ebins = (const float*)d_in[6];
  const float* pemb  = (const float*)d_in[7];
  const float* eemb  = (const float*)d_in[8];
  // per-predictor params start: dur=9, pit=19, ene=29
  // order: w1,b1,g1,be1,w2,b2,g2,be2,wl,bl

  float* out = (float*)d_out;
  // output offsets
  float* o_xexp  = out;                               // 32*2048*256
  float* o_pit   = out + (size_t)16777216;            // 16384
  float* o_ene   = o_pit + 16384;
  float* o_ldur  = o_ene + 16384;
  float* o_dur   = o_ldur + 16384;
  float* o_mlen  = o_dur + 16384;                     // 32
  float* o_mmask = o_mlen + 32;                       // 65536

  float* ws = (float*)d_ws;
  float* h1   = ws;                      // 16384*256
  float* h2   = h1 + (size_t)MM * HH;
  float* x1   = h2 + (size_t)MM * HH;
  float* pred = x1 + (size_t)MM * HH;    // 16384
  int*   cum  = (int*)(pred + MM);       // 16384 ints
  int*   mlw  = cum + MM;                // 32 ints

  dim3 cgrid(MM / TM, HH / TN);
  dim3 cblk(256);
  dim3 rgrid(MM / 4);

  // helper macro to run one predictor: input Xin, params base pi, ctrl, outputs
  #define RUN_PRED(Xin, pi, ctrlp, outp) do {                                   \
    conv_k3<<<cgrid, cblk, 0, stream>>>((const float*)(Xin),                    \
        (const float*)d_in[(pi)+0], (const float*)d_in[(pi)+1], h1);            \
    ln256<<<rgrid, 256, 0, stream>>>(h1, (const float*)d_in[(pi)+2],            \
        (const float*)d_in[(pi)+3]);                                            \
    conv_k3<<<cgrid, cblk, 0, stream>>>(h1,                                     \
        (const float*)d_in[(pi)+4], (const float*)d_in[(pi)+5], h2);            \
    ln256<<<rgrid, 256, 0, stream>>>(h2, (const float*)d_in[(pi)+6],            \
        (const float*)d_in[(pi)+7]);                                            \
    linear_head<<<rgrid, 256, 0, stream>>>(h2, (const float*)d_in[(pi)+8],      \
        (const float*)d_in[(pi)+9], smask, (ctrlp), (outp), pred);              \
  } while (0)

  // duration predictor (on x), no ctrl scaling of log_dur
  RUN_PRED(x, 9, (const float*)nullptr, o_ldur);
  dur_post<<<BB, 512, 0, stream>>>(pred, dc, o_dur, o_mlen, cum, mlw);

  // pitch predictor (on x)
  RUN_PRED(x, 19, pc, o_pit);
  bucket_add<<<rgrid, 256, 0, stream>>>(x, pred, pbins, pemb, x1);

  // energy predictor (on x1)
  RUN_PRED(x1, 29, ec, o_ene);
  bucket_add<<<rgrid, 256, 0, stream>>>(x1, pred, ebins, eemb, x1);

  // length regulator
  dim3 ggrid(MAXMEL / 4, BB);
  gather_expand<<<ggrid, 256, 0, stream>>>(x1, cum, mlw, o_xexp, o_mmask);

  #undef RUN_PRED
}

// Round 2
// 523.408 us; speedup vs baseline: 1.2584x; 1.2584x over previous
//
#include <hip/hip_runtime.h>
#include <stdint.h>

#define BB 32
#define SS 512
#define HH 256
#define MM (BB*SS)     // 16384 rows
#define MAXMEL 2048

typedef _Float16 f16;
typedef _Float16 f16x4 __attribute__((ext_vector_type(4)));
typedef _Float16 f16x8 __attribute__((ext_vector_type(8)));
typedef float    f32x16 __attribute__((ext_vector_type(16)));

// ---------------- split-f16 MFMA conv1d (K=3 SAME, 256->256) ----------------
// GEMM: M=16384, N=256, K=768. Block tile 128x128, 4 waves (2x2), wave tile
// 64x64 as 2x2 frags of 32x32. BK=32 f32 -> hi/lo f16 planes, 3-product split:
// Ahi*Bhi + Ahi*Blo + Alo*Bhi  (~f32 accuracy).
// LDS: 2048 chunks of 16B (32KB), chunk id c:
//   A: c =        p*512 + g*128 + row   (p=plane, g=k-group of 8 f16, row 0..127)
//   B: c = 1024 + p*512 + g*128 + col
// Staged with global_load_lds(16B): wave-uniform 1KB segments, per-lane source.
__global__ __launch_bounds__(256) void conv_mfma(
    const f16* __restrict__ Xhi, const f16* __restrict__ Xlo,   // [MM,256]
    const f16* __restrict__ Whi, const f16* __restrict__ Wlo,   // [256,768] (n-major)
    const float* __restrict__ bias,
    const f16* __restrict__ zp,                                  // zero page
    f16* __restrict__ Yhi, f16* __restrict__ Ylo)                // [MM,256]
{
  __shared__ f16 sm[16384];  // 32KB
  const int tid  = threadIdx.x;
  const int lane = tid & 63, wid = tid >> 6;
  const int bm = blockIdx.x, bn = blockIdx.y;
  const int l31 = lane & 31, half = lane >> 5;
  const int wr = wid >> 1, wc = wid & 1;

  f32x16 acc[2][2];
  #pragma unroll
  for (int mi = 0; mi < 2; ++mi)
    #pragma unroll
    for (int ni = 0; ni < 2; ++ni) acc[mi][ni] = (f32x16)0.f;

  const int cbase = wid * 8 * 64 + lane;

  for (int step = 0; step < 24; ++step) {
    const int ktap = step >> 3;          // 0,1,2
    const int cb   = (step & 7) << 5;    // 0..224
    __syncthreads();                     // protect LDS reuse
    #pragma unroll
    for (int i = 0; i < 8; ++i) {
      int c   = cbase + i * 64;
      int isB = c >> 10;
      int cc  = c & 1023;
      int p   = cc >> 9;
      int g   = (cc >> 7) & 3;
      int idx = cc & 127;
      const f16* src;
      if (isB) {
        int n = bn * 128 + idx;
        src = (p ? Wlo : Whi) + (size_t)n * 768 + ktap * 256 + cb + g * 8;
      } else {
        int r = bm * 128 + idx;
        int s = (r & 511) + ktap - 1;
        if ((unsigned)s < 512u)
          src = (p ? Xlo : Xhi) + (size_t)(r + ktap - 1) * 256 + cb + g * 8;
        else
          src = zp;
      }
      __builtin_amdgcn_global_load_lds(
          (const __attribute__((address_space(1))) void*)src,
          (__attribute__((address_space(3))) void*)(sm + (size_t)c * 8),
          16, 0, 0);
    }
    __syncthreads();                     // drains vmcnt before barrier

    #pragma unroll
    for (int kkh = 0; kkh < 2; ++kkh) {
      const int gg = kkh * 2 + half;     // k-group for this lane-half
      f16x8 a[2][2], b[2][2];            // [plane][mi/ni]
      #pragma unroll
      for (int p = 0; p < 2; ++p)
        #pragma unroll
        for (int q = 0; q < 2; ++q) {
          a[p][q] = *(const f16x8*)(sm + ((size_t)(p*512 + gg*128 + wr*64 + q*32 + l31)) * 8);
          b[p][q] = *(const f16x8*)(sm + ((size_t)(1024 + p*512 + gg*128 + wc*64 + q*32 + l31)) * 8);
        }
      #pragma unroll
      for (int mi = 0; mi < 2; ++mi)
        #pragma unroll
        for (int ni = 0; ni < 2; ++ni) {
          acc[mi][ni] = __builtin_amdgcn_mfma_f32_32x32x16_f16(a[0][mi], b[0][ni], acc[mi][ni], 0, 0, 0);
          acc[mi][ni] = __builtin_amdgcn_mfma_f32_32x32x16_f16(a[0][mi], b[1][ni], acc[mi][ni], 0, 0, 0);
          acc[mi][ni] = __builtin_amdgcn_mfma_f32_32x32x16_f16(a[1][mi], b[0][ni], acc[mi][ni], 0, 0, 0);
        }
    }
  }

  // epilogue: +bias, ReLU, split to hi/lo planes.
  // C/D layout (verified m74/m101): col=lane&31, row=(reg&3)+8*(reg>>2)+4*(lane>>5)
  #pragma unroll
  for (int mi = 0; mi < 2; ++mi)
    #pragma unroll
    for (int ni = 0; ni < 2; ++ni) {
      int colg = bn * 128 + wc * 64 + ni * 32 + l31;
      float bv = bias[colg];
      #pragma unroll
      for (int r = 0; r < 16; ++r) {
        int rowl = (r & 3) + 8 * (r >> 2) + 4 * half;
        size_t rowg = (size_t)bm * 128 + wr * 64 + mi * 32 + rowl;
        float v = acc[mi][ni][r] + bv;
        v = fmaxf(v, 0.f);
        f16 h = (f16)v;
        f16 l = (f16)(v - (float)h);
        Yhi[rowg * 256 + colg] = h;
        Ylo[rowg * 256 + colg] = l;
      }
    }
}

// ---------------- weight transpose + split: W[768,256] -> Wt planes [256,768] ----------------
__global__ __launch_bounds__(256) void wsplit_t(
    const float* __restrict__ W, f16* __restrict__ Thi, f16* __restrict__ Tlo)
{
  __shared__ float t[32][33];
  int bk = blockIdx.x, bn = blockIdx.y;   // grid (24, 8)
  int tt = threadIdx.x;
  int r = tt >> 3, c4 = (tt & 7) * 4;
  float4 v = *(const float4*)(W + (size_t)(bk * 32 + r) * 256 + bn * 32 + c4);
  t[r][c4 + 0] = v.x; t[r][c4 + 1] = v.y; t[r][c4 + 2] = v.z; t[r][c4 + 3] = v.w;
  __syncthreads();
  int n = tt >> 3, k4 = (tt & 7) * 4;
  f16x4 hi, lo;
  #pragma unroll
  for (int j = 0; j < 4; ++j) {
    float x = t[k4 + j][n];
    f16 h = (f16)x;
    hi[j] = h;
    lo[j] = (f16)(x - (float)h);
  }
  *(f16x4*)(Thi + (size_t)(bn * 32 + n) * 768 + bk * 32 + k4) = hi;
  *(f16x4*)(Tlo + (size_t)(bn * 32 + n) * 768 + bk * 32 + k4) = lo;
}

// ---------------- split f32 -> hi/lo planes ----------------
__global__ __launch_bounds__(256) void split2(
    const float* __restrict__ X, f16* __restrict__ Hi, f16* __restrict__ Lo)
{
  size_t i = ((size_t)blockIdx.x * 256 + threadIdx.x) * 4;
  float4 v = *(const float4*)(X + i);
  f16x4 h, l;
  float vv[4] = {v.x, v.y, v.z, v.w};
  #pragma unroll
  for (int j = 0; j < 4; ++j) {
    f16 hh = (f16)vv[j];
    h[j] = hh;
    l[j] = (f16)(vv[j] - (float)hh);
  }
  *(f16x4*)(Hi + i) = h;
  *(f16x4*)(Lo + i) = l;
}

// ---------------- LayerNorm over 256, planes in-place ----------------
__global__ __launch_bounds__(256) void ln_planes(
    f16* __restrict__ Phi, f16* __restrict__ Plo,
    const float* __restrict__ g, const float* __restrict__ be)
{
  int row  = blockIdx.x * 4 + (threadIdx.x >> 6);
  int lane = threadIdx.x & 63;
  size_t base = (size_t)row * HH + lane * 4;
  f16x4 h = *(const f16x4*)(Phi + base);
  f16x4 l = *(const f16x4*)(Plo + base);
  float v[4];
  #pragma unroll
  for (int j = 0; j < 4; ++j) v[j] = (float)h[j] + (float)l[j];
  float s = v[0] + v[1] + v[2] + v[3];
  float q = v[0]*v[0] + v[1]*v[1] + v[2]*v[2] + v[3]*v[3];
  #pragma unroll
  for (int d = 32; d > 0; d >>= 1) { s += __shfl_xor(s, d); q += __shfl_xor(q, d); }
  float mean = s * (1.f / 256.f);
  float var  = q * (1.f / 256.f) - mean * mean;
  float inv  = 1.0f / sqrtf(var + 1e-5f);
  float4 gg = *(const float4*)(g + lane * 4);
  float4 bb = *(const float4*)(be + lane * 4);
  float gv[4] = {gg.x, gg.y, gg.z, gg.w};
  float bv[4] = {bb.x, bb.y, bb.z, bb.w};
  #pragma unroll
  for (int j = 0; j < 4; ++j) {
    float o = (v[j] - mean) * inv * gv[j] + bv[j];
    f16 hh = (f16)o;
    h[j] = hh;
    l[j] = (f16)(o - (float)hh);
  }
  *(f16x4*)(Phi + base) = h;
  *(f16x4*)(Plo + base) = l;
}

// ---------------- linear head from planes ----------------
__global__ __launch_bounds__(256) void head_planes(
    const f16* __restrict__ Hhi, const f16* __restrict__ Hlo,
    const float* __restrict__ wl, const float* __restrict__ bl,
    const unsigned char* __restrict__ mask,
    const float* __restrict__ ctrl,
    float* __restrict__ out_a, float* __restrict__ out_b)
{
  int row  = blockIdx.x * 4 + (threadIdx.x >> 6);
  int lane = threadIdx.x & 63;
  size_t base = (size_t)row * HH + lane * 4;
  f16x4 h = *(const f16x4*)(Hhi + base);
  f16x4 l = *(const f16x4*)(Hlo + base);
  float4 w = *(const float4*)(wl + lane * 4);
  float s = ((float)h[0] + (float)l[0]) * w.x + ((float)h[1] + (float)l[1]) * w.y +
            ((float)h[2] + (float)l[2]) * w.z + ((float)h[3] + (float)l[3]) * w.w;
  #pragma unroll
  for (int d = 32; d > 0; d >>= 1) s += __shfl_xor(s, d);
  if (lane == 0) {
    float v = s + bl[0];
    if (mask[row]) v = 0.f;
    if (ctrl) v *= ctrl[0];
    out_a[row] = v;
    out_b[row] = v;
  }
}

// ---------------- bucketize + emb add (planes -> planes) ----------------
__global__ __launch_bounds__(256) void bucket_add_planes(
    const f16* __restrict__ Xhi, const f16* __restrict__ Xlo,
    const float* __restrict__ pred, const float* __restrict__ bins,
    const float* __restrict__ emb,
    f16* __restrict__ Ohi, f16* __restrict__ Olo)
{
  int row  = blockIdx.x * 4 + (threadIdx.x >> 6);
  int lane = threadIdx.x & 63;
  float v = pred[row];
  int lo = 0, hi = 255;                 // searchsorted side='left' over 255 bins
  while (lo < hi) { int mid = (lo + hi) >> 1; if (bins[mid] < v) lo = mid + 1; else hi = mid; }
  size_t base = (size_t)row * HH + lane * 4;
  f16x4 xh = *(const f16x4*)(Xhi + base);
  f16x4 xl = *(const f16x4*)(Xlo + base);
  float4 e = *(const float4*)(emb + (size_t)lo * HH + lane * 4);
  float ev[4] = {e.x, e.y, e.z, e.w};
  #pragma unroll
  for (int j = 0; j < 4; ++j) {
    float o = (float)xh[j] + (float)xl[j] + ev[j];
    f16 hh = (f16)o;
    xh[j] = hh;
    xl[j] = (f16)(o - (float)hh);
  }
  *(f16x4*)(Ohi + base) = xh;
  *(f16x4*)(Olo + base) = xl;
}

// ---------------- duration post: dur, cumsum, mel_len ----------------
__global__ __launch_bounds__(512) void dur_post(
    const float* __restrict__ logdur, const float* __restrict__ dc,
    float* __restrict__ out_dur, float* __restrict__ out_mel_len,
    int* __restrict__ cum_ws, int* __restrict__ mel_len_ws)
{
  __shared__ int wsum[8];
  int b = blockIdx.x, t = threadIdx.x;
  float ld = logdur[b * SS + t];
  float d  = fmaxf(rintf(expf(ld) - 1.f) * dc[0], 0.f);
  out_dur[b * SS + t] = d;
  int di = (int)d;
  int lane = t & 63, w = t >> 6;
  int x = di;
  #pragma unroll
  for (int dd = 1; dd < 64; dd <<= 1) {
    int n = __shfl_up(x, dd);
    if (lane >= dd) x += n;
  }
  if (lane == 63) wsum[w] = x;
  __syncthreads();
  int off = 0;
  for (int i = 0; i < w; ++i) off += wsum[i];
  x += off;
  cum_ws[b * SS + t] = x;
  if (t == SS - 1) {
    int ml = min(x, MAXMEL);
    mel_len_ws[b] = ml;
    out_mel_len[b] = (float)ml;
  }
}

// ---------------- length regulator from planes ----------------
__global__ __launch_bounds__(256) void gather_planes(
    const f16* __restrict__ Xhi, const f16* __restrict__ Xlo,
    const int* __restrict__ cum, const int* __restrict__ mel_len_ws,
    float* __restrict__ out_x, float* __restrict__ out_mask)
{
  __shared__ int c[SS];
  int b   = blockIdx.y;
  int tid = threadIdx.x;
  c[tid]       = cum[b * SS + tid];
  c[tid + 256] = cum[b * SS + tid + 256];
  __syncthreads();
  int w = tid >> 6, lane = tid & 63;
  int t = blockIdx.x * 4 + w;
  int lo = 0, hi = SS;
  while (lo < hi) { int mid = (lo + hi) >> 1; if (c[mid] <= t) lo = mid + 1; else hi = mid; }
  int idx = min(lo, SS - 1);
  int ml  = mel_len_ws[b];
  bool m  = (t >= ml);
  float4 v = make_float4(0.f, 0.f, 0.f, 0.f);
  if (!m) {
    size_t base = ((size_t)b * SS + idx) * HH + lane * 4;
    f16x4 xh = *(const f16x4*)(Xhi + base);
    f16x4 xl = *(const f16x4*)(Xlo + base);
    v.x = (float)xh[0] + (float)xl[0];
    v.y = (float)xh[1] + (float)xl[1];
    v.z = (float)xh[2] + (float)xl[2];
    v.w = (float)xh[3] + (float)xl[3];
  }
  *(float4*)(out_x + ((size_t)b * MAXMEL + t) * HH + lane * 4) = v;
  if (lane == 0) out_mask[b * MAXMEL + t] = m ? 1.f : 0.f;
}

// ---------------- launcher ----------------
extern "C" void kernel_launch(void* const* d_in, const int* in_sizes, int n_in,
                              void* d_out, int out_size, void* d_ws, size_t ws_size,
                              hipStream_t stream) {
  const float* x     = (const float*)d_in[0];
  const unsigned char* smask = (const unsigned char*)d_in[1];
  const float* pc    = (const float*)d_in[2];
  const float* ec    = (const float*)d_in[3];
  const float* dc    = (const float*)d_in[4];
  const float* pbins = (const float*)d_in[5];
  const float* ebins = (const float*)d_in[6];
  const float* pemb  = (const float*)d_in[7];
  const float* eemb  = (const float*)d_in[8];

  float* out = (float*)d_out;
  float* o_xexp  = out;
  float* o_pit   = out + (size_t)16777216;
  float* o_ene   = o_pit + 16384;
  float* o_ldur  = o_ene + 16384;
  float* o_dur   = o_ldur + 16384;
  float* o_mlen  = o_dur + 16384;
  float* o_mmask = o_mlen + 32;

  // workspace layout (f16 plane pairs)
  const size_t PL = (size_t)MM * HH;           // 4,194,304 elements
  f16* XPh  = (f16*)d_ws;
  f16* XPl  = XPh + PL;
  f16* TPh  = XPl + PL;
  f16* TPl  = TPh + PL;
  f16* UPh  = TPl + PL;
  f16* UPl  = UPh + PL;
  f16* X1h  = UPl + PL;
  f16* X1l  = X1h + PL;
  f16* Wt   = X1l + PL;                        // 6 convs x 2 planes x 768*256
  const size_t WSZ = (size_t)768 * 256;
  f16* Wp[12];
  for (int i = 0; i < 12; ++i) Wp[i] = Wt + (size_t)i * WSZ;
  float* pred = (float*)(Wt + 12 * WSZ);
  int*   cum  = (int*)(pred + MM);
  int*   mlw  = cum + MM;
  f16*   zp   = (f16*)(mlw + 64);

  hipMemsetAsync(zp, 0, 4096, stream);

  dim3 wgrid(24, 8);
  // weight transpose+split: dur w1(9), dur w2(13), pit w1(19), pit w2(23), ene w1(29), ene w2(33)
  wsplit_t<<<wgrid, 256, 0, stream>>>((const float*)d_in[9],  Wp[0], Wp[1]);
  wsplit_t<<<wgrid, 256, 0, stream>>>((const float*)d_in[13], Wp[2], Wp[3]);
  wsplit_t<<<wgrid, 256, 0, stream>>>((const float*)d_in[19], Wp[4], Wp[5]);
  wsplit_t<<<wgrid, 256, 0, stream>>>((const float*)d_in[23], Wp[6], Wp[7]);
  wsplit_t<<<wgrid, 256, 0, stream>>>((const float*)d_in[29], Wp[8], Wp[9]);
  wsplit_t<<<wgrid, 256, 0, stream>>>((const float*)d_in[33], Wp[10], Wp[11]);

  split2<<<4096, 256, 0, stream>>>(x, XPh, XPl);

  dim3 cgrid(128, 2);
  dim3 rgrid(MM / 4);

  #define RUN_PRED(INh, INl, pi, wbase, ctrlp, outp)                              \
    do {                                                                          \
      conv_mfma<<<cgrid, 256, 0, stream>>>(INh, INl, Wp[wbase], Wp[wbase+1],      \
          (const float*)d_in[(pi)+1], zp, TPh, TPl);                              \
      ln_planes<<<rgrid, 256, 0, stream>>>(TPh, TPl,                              \
          (const float*)d_in[(pi)+2], (const float*)d_in[(pi)+3]);                \
      conv_mfma<<<cgrid, 256, 0, stream>>>(TPh, TPl, Wp[wbase+2], Wp[wbase+3],    \
          (const float*)d_in[(pi)+5], zp, UPh, UPl);                              \
      ln_planes<<<rgrid, 256, 0, stream>>>(UPh, UPl,                              \
          (const float*)d_in[(pi)+6], (const float*)d_in[(pi)+7]);                \
      head_planes<<<rgrid, 256, 0, stream>>>(UPh, UPl,                            \
          (const float*)d_in[(pi)+8], (const float*)d_in[(pi)+9], smask,          \
          (ctrlp), (outp), pred);                                                 \
    } while (0)

  // duration predictor (input X planes)
  RUN_PRED(XPh, XPl, 9, 0, (const float*)nullptr, o_ldur);
  dur_post<<<BB, 512, 0, stream>>>(pred, dc, o_dur, o_mlen, cum, mlw);

  // pitch predictor (input X planes), then x1 = x + pemb[bucket(pitch)]
  RUN_PRED(XPh, XPl, 19, 4, pc, o_pit);
  bucket_add_planes<<<rgrid, 256, 0, stream>>>(XPh, XPl, pred, pbins, pemb, X1h, X1l);

  // energy predictor (input X1 planes), then x2 = x1 + eemb[bucket(energy)] -> TP
  RUN_PRED(X1h, X1l, 29, 8, ec, o_ene);
  bucket_add_planes<<<rgrid, 256, 0, stream>>>(X1h, X1l, pred, ebins, eemb, TPh, TPl);

  // length regulator reads TP planes
  dim3 ggrid(MAXMEL / 4, BB);
  gather_planes<<<ggrid, 256, 0, stream>>>(TPh, TPl, cum, mlw, o_xexp, o_mmask);

  #undef RUN_PRED
}

// Round 3
// 475.167 us; speedup vs baseline: 1.3862x; 1.1015x over previous
//
#include <hip/hip_runtime.h>
#include <stdint.h>

#define BB 32
#define SS 512
#define HH 256
#define MM (BB*SS)     // 16384 rows
#define MAXMEL 2048

typedef _Float16 f16;
typedef _Float16 f16x4 __attribute__((ext_vector_type(4)));
typedef _Float16 f16x8 __attribute__((ext_vector_type(8)));
typedef float    f32x16 __attribute__((ext_vector_type(16)));

#define BAR() asm volatile("s_barrier" ::: "memory")
#define VMW16() asm volatile("s_waitcnt vmcnt(16)" ::: "memory")
#define VMW8()  asm volatile("s_waitcnt vmcnt(8)"  ::: "memory")
#define VMW0()  asm volatile("s_waitcnt vmcnt(0)"  ::: "memory")

// ---------------- split-f16 MFMA conv1d (K=3 SAME, 256->256) ----------------
// GEMM: M=16384, N=256, K=768 (3 taps x 256). Block tile 128x128, 4 waves
// (2x2), wave tile 64x64 as 2x2 frags of 32x32. 3-product split per K-step:
// Ahi*Bhi + Ahi*Blo + Alo*Bhi (~f32 accuracy).
// Pipeline: 3-deep LDS buffers (3 x 32KB), raw s_barrier + counted vmcnt(16).
// Per buffer: 2048 chunks of 16B, chunk id c:
//   A: c =        p*512 + g*128 + row   (p=plane, g=k-group of 8 f16, row 0..127)
//   B: c = 1024 + p*512 + g*128 + col
__global__ __launch_bounds__(256) void conv_mfma(
    const f16* __restrict__ Xhi, const f16* __restrict__ Xlo,   // [MM,256]
    const f16* __restrict__ Whi, const f16* __restrict__ Wlo,   // [256,768] (n-major)
    const float* __restrict__ bias,
    const f16* __restrict__ zp,                                  // zero page
    f16* __restrict__ Yhi, f16* __restrict__ Ylo)                // [MM,256]
{
  __shared__ __align__(16) f16 sm[49152];   // 3 x 16384 f16 = 96KB
  const int tid  = threadIdx.x;
  const int lane = tid & 63, wid = tid >> 6;
  const int bm = blockIdx.x, bn = blockIdx.y;
  const int l31 = lane & 31, half = lane >> 5;
  const int wr = wid >> 1, wc = wid & 1;

  // per-thread stage descriptors (8 chunks each), static-indexed
  const f16* sbase[8];
  int sr[8];
  #pragma unroll
  for (int i = 0; i < 8; ++i) {
    int c = wid * 512 + i * 64 + lane;
    if (c < 1024) {                      // A region
      int p = c >> 9, g = (c >> 7) & 3, row = c & 127;
      int r = bm * 128 + row;
      sr[i] = r & 511;                   // position within sequence
      sbase[i] = (p ? Xlo : Xhi) + (size_t)r * 256 + g * 8;
    } else {                             // B region
      int cc = c - 1024;
      int p = cc >> 9, g = (cc >> 7) & 3, col = cc & 127;
      sr[i] = -1;
      sbase[i] = (p ? Wlo : Whi) + (size_t)(bn * 128 + col) * 768 + g * 8;
    }
  }

  f32x16 acc[2][2];
  #pragma unroll
  for (int mi = 0; mi < 2; ++mi)
    #pragma unroll
    for (int ni = 0; ni < 2; ++ni) acc[mi][ni] = (f32x16)0.f;

  auto STAGE = [&](int buf, int step) {
    const int ktap = step >> 3;          // 0,1,2
    const int cb   = (step & 7) << 5;    // 0..224
    #pragma unroll
    for (int i = 0; i < 8; ++i) {
      int c = wid * 512 + i * 64 + lane;
      const f16* src;
      if (sr[i] >= 0) {
        int s = sr[i] + ktap - 1;
        src = ((unsigned)s < 512u) ? (sbase[i] + (ktap - 1) * 256 + cb) : zp;
      } else {
        src = sbase[i] + ktap * 256 + cb;
      }
      __builtin_amdgcn_global_load_lds(
          (const __attribute__((address_space(1))) void*)src,
          (__attribute__((address_space(3))) void*)(sm + buf * 16384 + c * 8),
          16, 0, 0);
    }
  };

  auto COMPUTE = [&](int buf) {
    const f16* Bp = sm + buf * 16384;
    #pragma unroll
    for (int kkh = 0; kkh < 2; ++kkh) {
      const int gg = kkh * 2 + half;
      f16x8 a[2][2], b[2][2];            // [plane][mi/ni]
      #pragma unroll
      for (int p = 0; p < 2; ++p)
        #pragma unroll
        for (int q = 0; q < 2; ++q) {
          a[p][q] = *(const f16x8*)(Bp + ((size_t)(p*512 + gg*128 + wr*64 + q*32 + l31)) * 8);
          b[p][q] = *(const f16x8*)(Bp + ((size_t)(1024 + p*512 + gg*128 + wc*64 + q*32 + l31)) * 8);
        }
      #pragma unroll
      for (int mi = 0; mi < 2; ++mi)
        #pragma unroll
        for (int ni = 0; ni < 2; ++ni) {
          acc[mi][ni] = __builtin_amdgcn_mfma_f32_32x32x16_f16(a[0][mi], b[0][ni], acc[mi][ni], 0, 0, 0);
          acc[mi][ni] = __builtin_amdgcn_mfma_f32_32x32x16_f16(a[0][mi], b[1][ni], acc[mi][ni], 0, 0, 0);
          acc[mi][ni] = __builtin_amdgcn_mfma_f32_32x32x16_f16(a[1][mi], b[0][ni], acc[mi][ni], 0, 0, 0);
        }
    }
  };

  // prologue: 3 tiles in flight
  STAGE(0, 0); STAGE(1, 1); STAGE(2, 2);
  VMW16();   // tile 0 landed (ours)
  BAR();     // tile 0 landed (everyone's)

  int c0 = 0, c1 = 1, c2 = 2;
  for (int t = 0; t < 21; ++t) {
    COMPUTE(c0);
    BAR();               // all waves done reading buf c0
    STAGE(c0, t + 3);    // refill with tile t+3
    VMW16();             // tile t+1 landed (ours)
    BAR();               // tile t+1 landed (everyone's)
    int tmp = c0; c0 = c1; c1 = c2; c2 = tmp;
  }
  // tail: tiles 21,22,23 in bufs c0,c1,c2
  COMPUTE(c0);
  VMW8();  BAR();        // tile 22 landed
  COMPUTE(c1);
  VMW0();  BAR();        // tile 23 landed
  COMPUTE(c2);

  // epilogue: +bias, ReLU, split to hi/lo planes.
  // C/D layout: col=lane&31, row=(reg&3)+8*(reg>>2)+4*(lane>>5)
  #pragma unroll
  for (int mi = 0; mi < 2; ++mi)
    #pragma unroll
    for (int ni = 0; ni < 2; ++ni) {
      int colg = bn * 128 + wc * 64 + ni * 32 + l31;
      float bv = bias[colg];
      #pragma unroll
      for (int r = 0; r < 16; ++r) {
        int rowl = (r & 3) + 8 * (r >> 2) + 4 * half;
        size_t rowg = (size_t)bm * 128 + wr * 64 + mi * 32 + rowl;
        float v = acc[mi][ni][r] + bv;
        v = fmaxf(v, 0.f);
        f16 h = (f16)v;
        f16 l = (f16)(v - (float)h);
        Yhi[rowg * 256 + colg] = h;
        Ylo[rowg * 256 + colg] = l;
      }
    }
}

// ---------------- weight transpose + split: W[768,256] -> Wt planes [256,768] ----------------
__global__ __launch_bounds__(256) void wsplit_t(
    const float* __restrict__ W, f16* __restrict__ Thi, f16* __restrict__ Tlo)
{
  __shared__ float t[32][33];
  int bk = blockIdx.x, bn = blockIdx.y;   // grid (24, 8)
  int tt = threadIdx.x;
  int r = tt >> 3, c4 = (tt & 7) * 4;
  float4 v = *(const float4*)(W + (size_t)(bk * 32 + r) * 256 + bn * 32 + c4);
  t[r][c4 + 0] = v.x; t[r][c4 + 1] = v.y; t[r][c4 + 2] = v.z; t[r][c4 + 3] = v.w;
  __syncthreads();
  int n = tt >> 3, k4 = (tt & 7) * 4;
  f16x4 hi, lo;
  #pragma unroll
  for (int j = 0; j < 4; ++j) {
    float x = t[k4 + j][n];
    f16 h = (f16)x;
    hi[j] = h;
    lo[j] = (f16)(x - (float)h);
  }
  *(f16x4*)(Thi + (size_t)(bn * 32 + n) * 768 + bk * 32 + k4) = hi;
  *(f16x4*)(Tlo + (size_t)(bn * 32 + n) * 768 + bk * 32 + k4) = lo;
}

// ---------------- split f32 -> hi/lo planes ----------------
__global__ __launch_bounds__(256) void split2(
    const float* __restrict__ X, f16* __restrict__ Hi, f16* __restrict__ Lo)
{
  size_t i = ((size_t)blockIdx.x * 256 + threadIdx.x) * 4;
  float4 v = *(const float4*)(X + i);
  f16x4 h, l;
  float vv[4] = {v.x, v.y, v.z, v.w};
  #pragma unroll
  for (int j = 0; j < 4; ++j) {
    f16 hh = (f16)vv[j];
    h[j] = hh;
    l[j] = (f16)(vv[j] - (float)hh);
  }
  *(f16x4*)(Hi + i) = h;
  *(f16x4*)(Lo + i) = l;
}

// ---------------- LayerNorm over 256, planes in-place ----------------
__global__ __launch_bounds__(256) void ln_planes(
    f16* __restrict__ Phi, f16* __restrict__ Plo,
    const float* __restrict__ g, const float* __restrict__ be)
{
  int row  = blockIdx.x * 4 + (threadIdx.x >> 6);
  int lane = threadIdx.x & 63;
  size_t base = (size_t)row * HH + lane * 4;
  f16x4 h = *(const f16x4*)(Phi + base);
  f16x4 l = *(const f16x4*)(Plo + base);
  float v[4];
  #pragma unroll
  for (int j = 0; j < 4; ++j) v[j] = (float)h[j] + (float)l[j];
  float s = v[0] + v[1] + v[2] + v[3];
  float q = v[0]*v[0] + v[1]*v[1] + v[2]*v[2] + v[3]*v[3];
  #pragma unroll
  for (int d = 32; d > 0; d >>= 1) { s += __shfl_xor(s, d); q += __shfl_xor(q, d); }
  float mean = s * (1.f / 256.f);
  float var  = q * (1.f / 256.f) - mean * mean;
  float inv  = 1.0f / sqrtf(var + 1e-5f);
  float4 gg = *(const float4*)(g + lane * 4);
  float4 bb = *(const float4*)(be + lane * 4);
  float gv[4] = {gg.x, gg.y, gg.z, gg.w};
  float bv[4] = {bb.x, bb.y, bb.z, bb.w};
  #pragma unroll
  for (int j = 0; j < 4; ++j) {
    float o = (v[j] - mean) * inv * gv[j] + bv[j];
    f16 hh = (f16)o;
    h[j] = hh;
    l[j] = (f16)(o - (float)hh);
  }
  *(f16x4*)(Phi + base) = h;
  *(f16x4*)(Plo + base) = l;
}

// ---------------- linear head from planes ----------------
__global__ __launch_bounds__(256) void head_planes(
    const f16* __restrict__ Hhi, const f16* __restrict__ Hlo,
    const float* __restrict__ wl, const float* __restrict__ bl,
    const unsigned char* __restrict__ mask,
    const float* __restrict__ ctrl,
    float* __restrict__ out_a, float* __restrict__ out_b)
{
  int row  = blockIdx.x * 4 + (threadIdx.x >> 6);
  int lane = threadIdx.x & 63;
  size_t base = (size_t)row * HH + lane * 4;
  f16x4 h = *(const f16x4*)(Hhi + base);
  f16x4 l = *(const f16x4*)(Hlo + base);
  float4 w = *(const float4*)(wl + lane * 4);
  float s = ((float)h[0] + (float)l[0]) * w.x + ((float)h[1] + (float)l[1]) * w.y +
            ((float)h[2] + (float)l[2]) * w.z + ((float)h[3] + (float)l[3]) * w.w;
  #pragma unroll
  for (int d = 32; d > 0; d >>= 1) s += __shfl_xor(s, d);
  if (lane == 0) {
    float v = s + bl[0];
    if (mask[row]) v = 0.f;
    if (ctrl) v *= ctrl[0];
    out_a[row] = v;
    out_b[row] = v;
  }
}

// ---------------- bucketize + emb add (planes -> planes) ----------------
__global__ __launch_bounds__(256) void bucket_add_planes(
    const f16* __restrict__ Xhi, const f16* __restrict__ Xlo,
    const float* __restrict__ pred, const float* __restrict__ bins,
    const float* __restrict__ emb,
    f16* __restrict__ Ohi, f16* __restrict__ Olo)
{
  int row  = blockIdx.x * 4 + (threadIdx.x >> 6);
  int lane = threadIdx.x & 63;
  float v = pred[row];
  int lo = 0, hi = 255;
  while (lo < hi) { int mid = (lo + hi) >> 1; if (bins[mid] < v) lo = mid + 1; else hi = mid; }
  size_t base = (size_t)row * HH + lane * 4;
  f16x4 xh = *(const f16x4*)(Xhi + base);
  f16x4 xl = *(const f16x4*)(Xlo + base);
  float4 e = *(const float4*)(emb + (size_t)lo * HH + lane * 4);
  float ev[4] = {e.x, e.y, e.z, e.w};
  #pragma unroll
  for (int j = 0; j < 4; ++j) {
    float o = (float)xh[j] + (float)xl[j] + ev[j];
    f16 hh = (f16)o;
    xh[j] = hh;
    xl[j] = (f16)(o - (float)hh);
  }
  *(f16x4*)(Ohi + base) = xh;
  *(f16x4*)(Olo + base) = xl;
}

// ---------------- duration post: dur, cumsum, mel_len ----------------
__global__ __launch_bounds__(512) void dur_post(
    const float* __restrict__ logdur, const float* __restrict__ dc,
    float* __restrict__ out_dur, float* __restrict__ out_mel_len,
    int* __restrict__ cum_ws, int* __restrict__ mel_len_ws)
{
  __shared__ int wsum[8];
  int b = blockIdx.x, t = threadIdx.x;
  float ld = logdur[b * SS + t];
  float d  = fmaxf(rintf(expf(ld) - 1.f) * dc[0], 0.f);
  out_dur[b * SS + t] = d;
  int di = (int)d;
  int lane = t & 63, w = t >> 6;
  int x = di;
  #pragma unroll
  for (int dd = 1; dd < 64; dd <<= 1) {
    int n = __shfl_up(x, dd);
    if (lane >= dd) x += n;
  }
  if (lane == 63) wsum[w] = x;
  __syncthreads();
  int off = 0;
  for (int i = 0; i < w; ++i) off += wsum[i];
  x += off;
  cum_ws[b * SS + t] = x;
  if (t == SS - 1) {
    int ml = min(x, MAXMEL);
    mel_len_ws[b] = ml;
    out_mel_len[b] = (float)ml;
  }
}

// ---------------- length regulator from planes ----------------
__global__ __launch_bounds__(256) void gather_planes(
    const f16* __restrict__ Xhi, const f16* __restrict__ Xlo,
    const int* __restrict__ cum, const int* __restrict__ mel_len_ws,
    float* __restrict__ out_x, float* __restrict__ out_mask)
{
  __shared__ int c[SS];
  int b   = blockIdx.y;
  int tid = threadIdx.x;
  c[tid]       = cum[b * SS + tid];
  c[tid + 256] = cum[b * SS + tid + 256];
  __syncthreads();
  int w = tid >> 6, lane = tid & 63;
  int t = blockIdx.x * 4 + w;
  int lo = 0, hi = SS;
  while (lo < hi) { int mid = (lo + hi) >> 1; if (c[mid] <= t) lo = mid + 1; else hi = mid; }
  int idx = min(lo, SS - 1);
  int ml  = mel_len_ws[b];
  bool m  = (t >= ml);
  float4 v = make_float4(0.f, 0.f, 0.f, 0.f);
  if (!m) {
    size_t base = ((size_t)b * SS + idx) * HH + lane * 4;
    f16x4 xh = *(const f16x4*)(Xhi + base);
    f16x4 xl = *(const f16x4*)(Xlo + base);
    v.x = (float)xh[0] + (float)xl[0];
    v.y = (float)xh[1] + (float)xl[1];
    v.z = (float)xh[2] + (float)xl[2];
    v.w = (float)xh[3] + (float)xl[3];
  }
  *(float4*)(out_x + ((size_t)b * MAXMEL + t) * HH + lane * 4) = v;
  if (lane == 0) out_mask[b * MAXMEL + t] = m ? 1.f : 0.f;
}

// ---------------- launcher ----------------
extern "C" void kernel_launch(void* const* d_in, const int* in_sizes, int n_in,
                              void* d_out, int out_size, void* d_ws, size_t ws_size,
                              hipStream_t stream) {
  const float* x     = (const float*)d_in[0];
  const unsigned char* smask = (const unsigned char*)d_in[1];
  const float* pc    = (const float*)d_in[2];
  const float* ec    = (const float*)d_in[3];
  const float* dc    = (const float*)d_in[4];
  const float* pbins = (const float*)d_in[5];
  const float* ebins = (const float*)d_in[6];
  const float* pemb  = (const float*)d_in[7];
  const float* eemb  = (const float*)d_in[8];

  float* out = (float*)d_out;
  float* o_xexp  = out;
  float* o_pit   = out + (size_t)16777216;
  float* o_ene   = o_pit + 16384;
  float* o_ldur  = o_ene + 16384;
  float* o_dur   = o_ldur + 16384;
  float* o_mlen  = o_dur + 16384;
  float* o_mmask = o_mlen + 32;

  const size_t PL = (size_t)MM * HH;
  f16* XPh  = (f16*)d_ws;
  f16* XPl  = XPh + PL;
  f16* TPh  = XPl + PL;
  f16* TPl  = TPh + PL;
  f16* UPh  = TPl + PL;
  f16* UPl  = UPh + PL;
  f16* X1h  = UPl + PL;
  f16* X1l  = X1h + PL;
  f16* Wt   = X1l + PL;
  const size_t WSZ = (size_t)768 * 256;
  f16* Wp[12];
  for (int i = 0; i < 12; ++i) Wp[i] = Wt + (size_t)i * WSZ;
  float* pred = (float*)(Wt + 12 * WSZ);
  int*   cum  = (int*)(pred + MM);
  int*   mlw  = cum + MM;
  f16*   zp   = (f16*)(mlw + 64);

  hipMemsetAsync(zp, 0, 4096, stream);

  dim3 wgrid(24, 8);
  wsplit_t<<<wgrid, 256, 0, stream>>>((const float*)d_in[9],  Wp[0], Wp[1]);
  wsplit_t<<<wgrid, 256, 0, stream>>>((const float*)d_in[13], Wp[2], Wp[3]);
  wsplit_t<<<wgrid, 256, 0, stream>>>((const float*)d_in[19], Wp[4], Wp[5]);
  wsplit_t<<<wgrid, 256, 0, stream>>>((const float*)d_in[23], Wp[6], Wp[7]);
  wsplit_t<<<wgrid, 256, 0, stream>>>((const float*)d_in[29], Wp[8], Wp[9]);
  wsplit_t<<<wgrid, 256, 0, stream>>>((const float*)d_in[33], Wp[10], Wp[11]);

  split2<<<4096, 256, 0, stream>>>(x, XPh, XPl);

  dim3 cgrid(128, 2);
  dim3 rgrid(MM / 4);

  #define RUN_PRED(INh, INl, pi, wbase, ctrlp, outp)                              \
    do {                                                                          \
      conv_mfma<<<cgrid, 256, 0, stream>>>(INh, INl, Wp[wbase], Wp[wbase+1],      \
          (const float*)d_in[(pi)+1], zp, TPh, TPl);                              \
      ln_planes<<<rgrid, 256, 0, stream>>>(TPh, TPl,                              \
          (const float*)d_in[(pi)+2], (const float*)d_in[(pi)+3]);                \
      conv_mfma<<<cgrid, 256, 0, stream>>>(TPh, TPl, Wp[wbase+2], Wp[wbase+3],    \
          (const float*)d_in[(pi)+5], zp, UPh, UPl);                              \
      ln_planes<<<rgrid, 256, 0, stream>>>(UPh, UPl,                              \
          (const float*)d_in[(pi)+6], (const float*)d_in[(pi)+7]);                \
      head_planes<<<rgrid, 256, 0, stream>>>(UPh, UPl,                            \
          (const float*)d_in[(pi)+8], (const float*)d_in[(pi)+9], smask,          \
          (ctrlp), (outp), pred);                                                 \
    } while (0)

  RUN_PRED(XPh, XPl, 9, 0, (const float*)nullptr, o_ldur);
  dur_post<<<BB, 512, 0, stream>>>(pred, dc, o_dur, o_mlen, cum, mlw);

  RUN_PRED(XPh, XPl, 19, 4, pc, o_pit);
  bucket_add_planes<<<rgrid, 256, 0, stream>>>(XPh, XPl, pred, pbins, pemb, X1h, X1l);

  RUN_PRED(X1h, X1l, 29, 8, ec, o_ene);
  bucket_add_planes<<<rgrid, 256, 0, stream>>>(X1h, X1l, pred, ebins, eemb, TPh, TPl);

  dim3 ggrid(MAXMEL / 4, BB);
  gather_planes<<<ggrid, 256, 0, stream>>>(TPh, TPl, cum, mlw, o_xexp, o_mmask);

  #undef RUN_PRED
}

// Round 4
// 287.536 us; speedup vs baseline: 2.2908x; 1.6525x over previous
//
#include <hip/hip_runtime.h>
#include <stdint.h>

#define BB 32
#define SS 512
#define HH 256
#define MM (BB*SS)     // 16384 rows
#define MAXMEL 2048

typedef _Float16 f16;
typedef _Float16 f16x4 __attribute__((ext_vector_type(4)));
typedef _Float16 f16x8 __attribute__((ext_vector_type(8)));
typedef float    f32x16 __attribute__((ext_vector_type(16)));

#define BAR()   asm volatile("s_barrier" ::: "memory")
#define VMW17() asm volatile("s_waitcnt vmcnt(17)" ::: "memory")
#define VMW0()  asm volatile("s_waitcnt vmcnt(0)"  ::: "memory")

// X' layout: [chanblk 8][row 16384][slot 4][8 f16], slot = ((chan>>3)&3) ^ (row&3)
__device__ __forceinline__ size_t xoff(int row, int chan) {
  int cbb = chan >> 5, cc = (chan >> 3) & 3, e = chan & 7;
  return ((size_t)cbb * MM + row) * 32 + ((cc ^ (row & 3)) << 3) + e;
}

// LDS map (bytes): [A buf0 20480][A buf1 20480][B buf0 49152][B buf1 49152]
//   zero blocks at 139264 and 159744 (64B each)
#define ABUFB 20480
#define BREG  40960
#define BBUFB 49152
#define ZOFF  139264
#define LDSSZ 159808

// ---------------- split-f16 MFMA conv1d (K=3 SAME, 256->256) ----------------
// Block tile 128x128, 4 waves (2x2), wave 64x64 as 2x2 frags of 32x32.
// 8 steps: step cb covers chans [cb*32,+32) x 3 taps. A staged once/step,
// reused across taps. 3-product split: Ahi*Bhi + Ahi*Blo + Alo*Bhi.
// All staging sources contiguous 1KB per instr; 68 instrs/step = 17/wave.
__global__ __launch_bounds__(256) void conv_mfma(
    const f16* __restrict__ Xhi, const f16* __restrict__ Xlo,   // X' layout
    const f16* __restrict__ Whi, const f16* __restrict__ Wlo,   // packed
    const float* __restrict__ bias,
    f16* __restrict__ Yhi, f16* __restrict__ Ylo)                // X' layout
{
  __shared__ __align__(16) unsigned char smem[LDSSZ];
  const int tid  = threadIdx.x;
  const int lane = tid & 63, wid = tid >> 6;
  const int bm = blockIdx.x, bn = blockIdx.y;
  const int l31 = lane & 31, half = lane >> 5;
  const int hx = half << 4;
  const int wr = wid >> 1, wc = wid & 1;

  // ---- fragment read addresses ----
  int a_addr[3][2][2];   // [tap][q(mi)][p], bits[4:5] hold swizzle key
  #pragma unroll
  for (int tap = 0; tap < 3; ++tap)
    #pragma unroll
    for (int q = 0; q < 2; ++q) {
      int row_l = wr * 64 + q * 32 + l31;
      int s_t = (bm & 3) * 128 + row_l + tap - 1;
      bool valid = (unsigned)s_t < 512u;
      int lrow = row_l + tap + 15;
      int base = (lrow << 6) | ((lrow & 3) << 4);
      #pragma unroll
      for (int p = 0; p < 2; ++p)
        a_addr[tap][q][p] = valid ? (base + p * 10240) : ZOFF;
    }
  int b_addr[2][2];      // [buf][n(ni)]
  #pragma unroll
  for (int n = 0; n < 2; ++n) {
    int col_l = wc * 64 + n * 32 + l31;
    int bb = BREG + col_l * 64 + ((col_l & 3) << 4);
    b_addr[0][n] = bb; b_addr[1][n] = bb + BBUFB;
  }

  f32x16 acc[2][2];
  #pragma unroll
  for (int mi = 0; mi < 2; ++mi)
    #pragma unroll
    for (int ni = 0; ni < 2; ++ni) acc[mi][ni] = (f32x16)0.f;

  // ---- staging: 68 contiguous-1KB instrs, 17 per wave ----
  auto STAGE = [&](int buf, int cb) {
    #pragma unroll
    for (int i = 0; i < 17; ++i) {
      int j = wid * 17 + i;
      const f16* src;
      int dst;
      if (j < 20) {                       // A: 2 planes x 10 instrs (160 rows)
        int p = j / 10, ii = j % 10;
        int rowstart = bm * 128 - 16 + ii * 16;
        rowstart = rowstart < 0 ? 0 : (rowstart > MM - 16 ? MM - 16 : rowstart);
        src = (p ? Xlo : Xhi) + ((size_t)cb * MM + rowstart) * 32 + lane * 8;
        dst = buf * ABUFB + p * 10240 + ii * 1024 + lane * 16;
      } else {                            // B: 2 planes x 24 instrs
        int jj = j - 20;
        int p = jj / 24, rest = jj % 24;
        src = (p ? Wlo : Whi) + (size_t)(bn * 8 + cb) * 12288 + rest * 512 + lane * 8;
        dst = BREG + buf * BBUFB + p * 24576 + rest * 1024 + lane * 16;
      }
      __builtin_amdgcn_global_load_lds(
          (const __attribute__((address_space(1))) void*)src,
          (__attribute__((address_space(3))) void*)(smem + dst), 16, 0, 0);
    }
  };

  auto COMP = [&](int buf) {
    #pragma unroll
    for (int tap = 0; tap < 3; ++tap) {
      #pragma unroll
      for (int kkh = 0; kkh < 2; ++kkh) {
        const int gx = (kkh << 5) | hx;    // gg = kkh*2+half at bits[4:5]
        f16x8 av[2][2], bv[2][2];
        #pragma unroll
        for (int p = 0; p < 2; ++p)
          #pragma unroll
          for (int q = 0; q < 2; ++q) {
            av[p][q] = *(const f16x8*)(smem + ((a_addr[tap][q][p] ^ gx) + buf * ABUFB));
            bv[p][q] = *(const f16x8*)(smem + ((b_addr[buf][q] ^ gx) + (p * 3 + tap) * 8192));
          }
        #pragma unroll
        for (int mi = 0; mi < 2; ++mi)
          #pragma unroll
          for (int ni = 0; ni < 2; ++ni) {
            acc[mi][ni] = __builtin_amdgcn_mfma_f32_32x32x16_f16(av[0][mi], bv[0][ni], acc[mi][ni], 0, 0, 0);
            acc[mi][ni] = __builtin_amdgcn_mfma_f32_32x32x16_f16(av[0][mi], bv[1][ni], acc[mi][ni], 0, 0, 0);
            acc[mi][ni] = __builtin_amdgcn_mfma_f32_32x32x16_f16(av[1][mi], bv[0][ni], acc[mi][ni], 0, 0, 0);
          }
      }
    }
  };

  // zero blocks for boundary-lane redirected reads
  if (tid < 4) {
    *(float4*)(smem + ZOFF + tid * 16) = make_float4(0.f, 0.f, 0.f, 0.f);
    *(float4*)(smem + ZOFF + ABUFB + tid * 16) = make_float4(0.f, 0.f, 0.f, 0.f);
  }
  STAGE(0, 0); STAGE(1, 1);
  __syncthreads();          // drains vmcnt+lgkm: steps 0,1 landed, zeros visible

  #pragma unroll
  for (int cb = 0; cb < 8; ++cb) {
    COMP(cb & 1);
    BAR();                  // all waves done reading buf cb&1
    if (cb < 6)      { STAGE(cb & 1, cb + 2); VMW17(); }
    else if (cb == 6){ VMW0(); }
    BAR();                  // next step's data landed everywhere
  }

  // epilogue: +bias, ReLU, split, store in X' layout
  #pragma unroll
  for (int mi = 0; mi < 2; ++mi)
    #pragma unroll
    for (int ni = 0; ni < 2; ++ni) {
      int colg = bn * 128 + wc * 64 + ni * 32 + l31;
      float bvs = bias[colg];
      int cbb = colg >> 5, cc = (colg >> 3) & 3, e = colg & 7;
      #pragma unroll
      for (int r = 0; r < 16; ++r) {
        int rowl = (r & 3) + 8 * (r >> 2) + 4 * half;
        int rowg = bm * 128 + wr * 64 + mi * 32 + rowl;
        float v = acc[mi][ni][r] + bvs;
        v = fmaxf(v, 0.f);
        f16 h = (f16)v;
        f16 l = (f16)(v - (float)h);
        size_t o = ((size_t)cbb * MM + rowg) * 32 + ((cc ^ (r & 3)) << 3) + e;
        Yhi[o] = h;
        Ylo[o] = l;
      }
    }
}

// ---------------- weight pack+split: W[768,256] -> packed planes ----------------
// packed: [bn 2][cb 8][tap 3][col 128][slot 4][8 f16], slot = gg ^ (col&3)
__global__ __launch_bounds__(256) void wsplit_pack(
    const float* __restrict__ W, f16* __restrict__ Thi, f16* __restrict__ Tlo)
{
  int id = blockIdx.x * 256 + threadIdx.x;    // [0, 24576)
  int slot = id & 3, col = (id >> 2) & 127;
  int t3 = id >> 9;
  int tap = t3 % 3, bc = t3 / 3;
  int cb = bc & 7, bnn = bc >> 3;
  int gg = slot ^ (col & 3);
  int chan = cb * 32 + gg * 8;
  int colg = bnn * 128 + col;
  f16x8 hi, lo;
  #pragma unroll
  for (int e = 0; e < 8; ++e) {
    float w = W[(size_t)(tap * 256 + chan + e) * 256 + colg];
    f16 h = (f16)w;
    hi[e] = h;
    lo[e] = (f16)(w - (float)h);
  }
  *(f16x8*)(Thi + (size_t)id * 8) = hi;
  *(f16x8*)(Tlo + (size_t)id * 8) = lo;
}

// ---------------- split f32 -> hi/lo planes (X' layout) ----------------
__global__ __launch_bounds__(256) void split2(
    const float* __restrict__ X, f16* __restrict__ Hi, f16* __restrict__ Lo)
{
  int id = blockIdx.x * 256 + threadIdx.x;    // [0, 524288)
  int row = id >> 5, c32 = id & 31;
  int chan = c32 * 8;
  const float* src = X + (size_t)row * 256 + chan;
  float4 v0 = *(const float4*)src;
  float4 v1 = *(const float4*)(src + 4);
  float vv[8] = {v0.x, v0.y, v0.z, v0.w, v1.x, v1.y, v1.z, v1.w};
  f16x8 h, l;
  #pragma unroll
  for (int j = 0; j < 8; ++j) {
    f16 hh = (f16)vv[j];
    h[j] = hh;
    l[j] = (f16)(vv[j] - (float)hh);
  }
  size_t o = xoff(row, chan);
  *(f16x8*)(Hi + o) = h;
  *(f16x8*)(Lo + o) = l;
}

// ---------------- LayerNorm over 256, planes in-place (X' layout) ----------------
__global__ __launch_bounds__(256) void ln_planes(
    f16* __restrict__ Phi, f16* __restrict__ Plo,
    const float* __restrict__ g, const float* __restrict__ be)
{
  int row  = blockIdx.x * 4 + (threadIdx.x >> 6);
  int lane = threadIdx.x & 63;
  size_t o = xoff(row, lane * 4);
  f16x4 h = *(const f16x4*)(Phi + o);
  f16x4 l = *(const f16x4*)(Plo + o);
  float v[4];
  #pragma unroll
  for (int j = 0; j < 4; ++j) v[j] = (float)h[j] + (float)l[j];
  float s = v[0] + v[1] + v[2] + v[3];
  float q = v[0]*v[0] + v[1]*v[1] + v[2]*v[2] + v[3]*v[3];
  #pragma unroll
  for (int d = 32; d > 0; d >>= 1) { s += __shfl_xor(s, d); q += __shfl_xor(q, d); }
  float mean = s * (1.f / 256.f);
  float var  = q * (1.f / 256.f) - mean * mean;
  float inv  = 1.0f / sqrtf(var + 1e-5f);
  float4 gg = *(const float4*)(g + lane * 4);
  float4 bb = *(const float4*)(be + lane * 4);
  float gv[4] = {gg.x, gg.y, gg.z, gg.w};
  float bv[4] = {bb.x, bb.y, bb.z, bb.w};
  #pragma unroll
  for (int j = 0; j < 4; ++j) {
    float oo = (v[j] - mean) * inv * gv[j] + bv[j];
    f16 hh = (f16)oo;
    h[j] = hh;
    l[j] = (f16)(oo - (float)hh);
  }
  *(f16x4*)(Phi + o) = h;
  *(f16x4*)(Plo + o) = l;
}

// ---------------- fused LayerNorm + linear head (no writeback) ----------------
__global__ __launch_bounds__(256) void lnhead(
    const f16* __restrict__ Phi, const f16* __restrict__ Plo,
    const float* __restrict__ g, const float* __restrict__ be,
    const float* __restrict__ wl, const float* __restrict__ bl,
    const unsigned char* __restrict__ mask, const float* __restrict__ ctrl,
    float* __restrict__ out_a, float* __restrict__ out_b)
{
  int row  = blockIdx.x * 4 + (threadIdx.x >> 6);
  int lane = threadIdx.x & 63;
  size_t o = xoff(row, lane * 4);
  f16x4 h = *(const f16x4*)(Phi + o);
  f16x4 l = *(const f16x4*)(Plo + o);
  float v[4];
  #pragma unroll
  for (int j = 0; j < 4; ++j) v[j] = (float)h[j] + (float)l[j];
  float s = v[0] + v[1] + v[2] + v[3];
  float q = v[0]*v[0] + v[1]*v[1] + v[2]*v[2] + v[3]*v[3];
  #pragma unroll
  for (int d = 32; d > 0; d >>= 1) { s += __shfl_xor(s, d); q += __shfl_xor(q, d); }
  float mean = s * (1.f / 256.f);
  float var  = q * (1.f / 256.f) - mean * mean;
  float inv  = 1.0f / sqrtf(var + 1e-5f);
  float4 gg = *(const float4*)(g + lane * 4);
  float4 bb = *(const float4*)(be + lane * 4);
  float4 ww = *(const float4*)(wl + lane * 4);
  float gv[4] = {gg.x, gg.y, gg.z, gg.w};
  float bv[4] = {bb.x, bb.y, bb.z, bb.w};
  float wv[4] = {ww.x, ww.y, ww.z, ww.w};
  float acc = 0.f;
  #pragma unroll
  for (int j = 0; j < 4; ++j)
    acc += ((v[j] - mean) * inv * gv[j] + bv[j]) * wv[j];
  #pragma unroll
  for (int d = 32; d > 0; d >>= 1) acc += __shfl_xor(acc, d);
  if (lane == 0) {
    float r = acc + bl[0];
    if (mask[row]) r = 0.f;
    if (ctrl) r *= ctrl[0];
    out_a[row] = r;
    out_b[row] = r;
  }
}

// ---------------- bucketize + emb add (X' planes -> X' planes) ----------------
__global__ __launch_bounds__(256) void bucket_add_planes(
    const f16* __restrict__ Xhi, const f16* __restrict__ Xlo,
    const float* __restrict__ pred, const float* __restrict__ bins,
    const float* __restrict__ emb,
    f16* __restrict__ Ohi, f16* __restrict__ Olo)
{
  int row  = blockIdx.x * 4 + (threadIdx.x >> 6);
  int lane = threadIdx.x & 63;
  float v = pred[row];
  int lo = 0, hi = 255;
  while (lo < hi) { int mid = (lo + hi) >> 1; if (bins[mid] < v) lo = mid + 1; else hi = mid; }
  size_t o = xoff(row, lane * 4);
  f16x4 xh = *(const f16x4*)(Xhi + o);
  f16x4 xl = *(const f16x4*)(Xlo + o);
  float4 e = *(const float4*)(emb + (size_t)lo * HH + lane * 4);
  float ev[4] = {e.x, e.y, e.z, e.w};
  #pragma unroll
  for (int j = 0; j < 4; ++j) {
    float oo = (float)xh[j] + (float)xl[j] + ev[j];
    f16 hh = (f16)oo;
    xh[j] = hh;
    xl[j] = (f16)(oo - (float)hh);
  }
  *(f16x4*)(Ohi + o) = xh;
  *(f16x4*)(Olo + o) = xl;
}

// ---------------- duration post: dur, cumsum, mel_len ----------------
__global__ __launch_bounds__(512) void dur_post(
    const float* __restrict__ logdur, const float* __restrict__ dc,
    float* __restrict__ out_dur, float* __restrict__ out_mel_len,
    int* __restrict__ cum_ws, int* __restrict__ mel_len_ws)
{
  __shared__ int wsum[8];
  int b = blockIdx.x, t = threadIdx.x;
  float ld = logdur[b * SS + t];
  float d  = fmaxf(rintf(expf(ld) - 1.f) * dc[0], 0.f);
  out_dur[b * SS + t] = d;
  int di = (int)d;
  int lane = t & 63, w = t >> 6;
  int x = di;
  #pragma unroll
  for (int dd = 1; dd < 64; dd <<= 1) {
    int n = __shfl_up(x, dd);
    if (lane >= dd) x += n;
  }
  if (lane == 63) wsum[w] = x;
  __syncthreads();
  int off = 0;
  for (int i = 0; i < w; ++i) off += wsum[i];
  x += off;
  cum_ws[b * SS + t] = x;
  if (t == SS - 1) {
    int ml = min(x, MAXMEL);
    mel_len_ws[b] = ml;
    out_mel_len[b] = (float)ml;
  }
}

// ---------------- length regulator from X' planes ----------------
__global__ __launch_bounds__(256) void gather_planes(
    const f16* __restrict__ Xhi, const f16* __restrict__ Xlo,
    const int* __restrict__ cum, const int* __restrict__ mel_len_ws,
    float* __restrict__ out_x, float* __restrict__ out_mask)
{
  __shared__ int c[SS];
  int b   = blockIdx.y;
  int tid = threadIdx.x;
  c[tid]       = cum[b * SS + tid];
  c[tid + 256] = cum[b * SS + tid + 256];
  __syncthreads();
  int w = tid >> 6, lane = tid & 63;
  int t = blockIdx.x * 4 + w;
  int lo = 0, hi = SS;
  while (lo < hi) { int mid = (lo + hi) >> 1; if (c[mid] <= t) lo = mid + 1; else hi = mid; }
  int idx = min(lo, SS - 1);
  int ml  = mel_len_ws[b];
  bool m  = (t >= ml);
  float4 v = make_float4(0.f, 0.f, 0.f, 0.f);
  if (!m) {
    size_t o = xoff((int)(b * SS + idx), lane * 4);
    f16x4 xh = *(const f16x4*)(Xhi + o);
    f16x4 xl = *(const f16x4*)(Xlo + o);
    v.x = (float)xh[0] + (float)xl[0];
    v.y = (float)xh[1] + (float)xl[1];
    v.z = (float)xh[2] + (float)xl[2];
    v.w = (float)xh[3] + (float)xl[3];
  }
  *(float4*)(out_x + ((size_t)b * MAXMEL + t) * HH + lane * 4) = v;
  if (lane == 0) out_mask[b * MAXMEL + t] = m ? 1.f : 0.f;
}

// ---------------- launcher ----------------
extern "C" void kernel_launch(void* const* d_in, const int* in_sizes, int n_in,
                              void* d_out, int out_size, void* d_ws, size_t ws_size,
                              hipStream_t stream) {
  const float* x     = (const float*)d_in[0];
  const unsigned char* smask = (const unsigned char*)d_in[1];
  const float* pc    = (const float*)d_in[2];
  const float* ec    = (const float*)d_in[3];
  const float* dc    = (const float*)d_in[4];
  const float* pbins = (const float*)d_in[5];
  const float* ebins = (const float*)d_in[6];
  const float* pemb  = (const float*)d_in[7];
  const float* eemb  = (const float*)d_in[8];

  float* out = (float*)d_out;
  float* o_xexp  = out;
  float* o_pit   = out + (size_t)16777216;
  float* o_ene   = o_pit + 16384;
  float* o_ldur  = o_ene + 16384;
  float* o_dur   = o_ldur + 16384;
  float* o_mlen  = o_dur + 16384;
  float* o_mmask = o_mlen + 32;

  const size_t PL = (size_t)MM * HH;
  f16* XPh  = (f16*)d_ws;
  f16* XPl  = XPh + PL;
  f16* TPh  = XPl + PL;
  f16* TPl  = TPh + PL;
  f16* UPh  = TPl + PL;
  f16* UPl  = UPh + PL;
  f16* X1h  = UPl + PL;
  f16* X1l  = X1h + PL;
  f16* Wt   = X1l + PL;
  const size_t WSZ = (size_t)768 * 256;
  f16* Wp[12];
  for (int i = 0; i < 12; ++i) Wp[i] = Wt + (size_t)i * WSZ;
  float* pred = (float*)(Wt + 12 * WSZ);
  int*   cum  = (int*)(pred + MM);
  int*   mlw  = cum + MM;

  dim3 wgrid(96);
  wsplit_pack<<<wgrid, 256, 0, stream>>>((const float*)d_in[9],  Wp[0], Wp[1]);
  wsplit_pack<<<wgrid, 256, 0, stream>>>((const float*)d_in[13], Wp[2], Wp[3]);
  wsplit_pack<<<wgrid, 256, 0, stream>>>((const float*)d_in[19], Wp[4], Wp[5]);
  wsplit_pack<<<wgrid, 256, 0, stream>>>((const float*)d_in[23], Wp[6], Wp[7]);
  wsplit_pack<<<wgrid, 256, 0, stream>>>((const float*)d_in[29], Wp[8], Wp[9]);
  wsplit_pack<<<wgrid, 256, 0, stream>>>((const float*)d_in[33], Wp[10], Wp[11]);

  split2<<<2048, 256, 0, stream>>>(x, XPh, XPl);

  dim3 cgrid(128, 2);
  dim3 rgrid(MM / 4);

  #define RUN_PRED(INh, INl, pi, wbase, ctrlp, outp)                              \
    do {                                                                          \
      conv_mfma<<<cgrid, 256, 0, stream>>>(INh, INl, Wp[wbase], Wp[wbase+1],      \
          (const float*)d_in[(pi)+1], TPh, TPl);                                  \
      ln_planes<<<rgrid, 256, 0, stream>>>(TPh, TPl,                              \
          (const float*)d_in[(pi)+2], (const float*)d_in[(pi)+3]);                \
      conv_mfma<<<cgrid, 256, 0, stream>>>(TPh, TPl, Wp[wbase+2], Wp[wbase+3],    \
          (const float*)d_in[(pi)+5], UPh, UPl);                                  \
      lnhead<<<rgrid, 256, 0, stream>>>(UPh, UPl,                                 \
          (const float*)d_in[(pi)+6], (const float*)d_in[(pi)+7],                 \
          (const float*)d_in[(pi)+8], (const float*)d_in[(pi)+9], smask,          \
          (ctrlp), (outp), pred);                                                 \
    } while (0)

  RUN_PRED(XPh, XPl, 9, 0, (const float*)nullptr, o_ldur);
  dur_post<<<BB, 512, 0, stream>>>(pred, dc, o_dur, o_mlen, cum, mlw);

  RUN_PRED(XPh, XPl, 19, 4, pc, o_pit);
  bucket_add_planes<<<rgrid, 256, 0, stream>>>(XPh, XPl, pred, pbins, pemb, X1h, X1l);

  RUN_PRED(X1h, X1l, 29, 8, ec, o_ene);
  bucket_add_planes<<<rgrid, 256, 0, stream>>>(X1h, X1l, pred, ebins, eemb, TPh, TPl);

  dim3 ggrid(MAXMEL / 4, BB);
  gather_planes<<<ggrid, 256, 0, stream>>>(TPh, TPl, cum, mlw, o_xexp, o_mmask);

  #undef RUN_PRED
}

// Round 5
// 231.325 us; speedup vs baseline: 2.8474x; 1.2430x over previous
//
#include <hip/hip_runtime.h>
#include <stdint.h>

#define BB 32
#define SS 512
#define HH 256
#define MM (BB*SS)     // 16384 rows
#define MAXMEL 2048

typedef _Float16 f16;
typedef _Float16 f16x4 __attribute__((ext_vector_type(4)));
typedef _Float16 f16x8 __attribute__((ext_vector_type(8)));
typedef float    f32x16 __attribute__((ext_vector_type(16)));

#define BAR()  asm volatile("s_barrier" ::: "memory")
#define VMW9() asm volatile("s_waitcnt vmcnt(9)" ::: "memory")
#define VMW0() asm volatile("s_waitcnt vmcnt(0)" ::: "memory")

// X' layout: [cb 16][row MM][slot 2][8 f16], slot = ((chan>>3)&1) ^ (row&1)
__device__ __forceinline__ size_t xoff(int row, int chan) {
  int cb = chan >> 4, cc = (chan >> 3) & 1, e = chan & 7;
  return ((size_t)cb * MM + row) * 16 + (size_t)(((cc ^ (row & 1)) << 3) + e);
}

// LDS map (bytes): B0 @0 (24576), B1 @24576, A0 @49152 (12288+64z), A1 @61504
#define BBUF 24576
#define AOFF 49152
#define ABUF 12352
#define AZ   61440          // A0 zero block; A1's lands at 73792
#define LDSSZ 73856
#define WSZ  ((size_t)768*256)

// ---------------- conv1d (K=3 SAME, 256->256), split-f16 MFMA ----------------
// 16 steps of (16 chans x 3 taps). Block 128x128, 4 waves (2x2), wave 64x64 as
// 2x2 frags of 32x32x16. 3-product split: Ahi*Bhi + Ahi*Blo + Alo*Bhi.
// RAW=0: z=predictor (2 weight/output sets), all 16 steps, f16-plane epilogue.
// RAW=1: z=K-half (steps z*8..+8), raw f32 partial epilogue (bias/relu later).
template<int NS, int RAW>
__global__ __launch_bounds__(256) void conv16(
    const f16* __restrict__ X0h, const f16* __restrict__ X0l,
    const f16* __restrict__ X1h_, const f16* __restrict__ X1l_,
    const f16* __restrict__ W0h, const f16* __restrict__ W0l,
    const f16* __restrict__ W1h, const f16* __restrict__ W1l,
    const float* __restrict__ bias0, const float* __restrict__ bias1,
    f16* __restrict__ Y0h, f16* __restrict__ Y0l,
    f16* __restrict__ Y1h, f16* __restrict__ Y1l,
    float* __restrict__ Craw)
{
  __shared__ __align__(16) unsigned char smem[LDSSZ];
  const int tid = threadIdx.x;
  const int lane = tid & 63, wid = tid >> 6;
  const int bm = blockIdx.x, bn = blockIdx.y, bz = blockIdx.z;
  const int l31 = lane & 31, half = lane >> 5;
  const int hx4 = half << 4;
  const int wr = wid >> 1, wc = wid & 1;

  const int s0 = RAW ? bz * 8 : 0;
  const f16* Xh = (RAW || bz == 0) ? X0h : X1h_;
  const f16* Xl = (RAW || bz == 0) ? X0l : X1l_;
  const f16* Wh = (RAW || bz == 0) ? W0h : W1h;
  const f16* Wl = (RAW || bz == 0) ? W0l : W1l;

  // stage descriptors: 9 instrs/thread/step (A 12 + B 24 = 36 per block)
  const f16* sb[9]; int sdst[9]; int sstr[9]; int sdb[9];
  #pragma unroll
  for (int i = 0; i < 9; ++i) {
    int j = wid * 9 + i;
    if (j < 12) {                 // A: 6 segs of 32 rows x 2 planes
      int p = j / 6, seg = j % 6;
      int rowstart = bm * 128 - 32 + seg * 32;
      rowstart = rowstart < 0 ? 0 : (rowstart > MM - 32 ? MM - 32 : rowstart);
      sb[i]   = (p ? Xl : Xh) + (size_t)rowstart * 16 + lane * 8;
      sstr[i] = MM * 16;
      sdst[i] = AOFF + p * 6144 + seg * 1024 + lane * 16;
      sdb[i]  = ABUF;
    } else {                      // B: [plane][tap][4 x 1KB]
      int jj = j - 12;
      int p = jj / 12, tap = (jj % 12) / 4, q4 = jj & 3;
      sb[i]   = (p ? Wl : Wh) + ((size_t)(bn * 16) * 3 + tap) * 2048 + q4 * 512 + lane * 8;
      sstr[i] = 6144;
      sdst[i] = p * 12288 + tap * 4096 + q4 * 1024 + lane * 16;
      sdb[i]  = BBUF;
    }
  }

  // fragment read addresses
  int a_addr[3][2][2];            // [tap][q(mi)][p]
  #pragma unroll
  for (int tap = 0; tap < 3; ++tap)
    #pragma unroll
    for (int q = 0; q < 2; ++q) {
      int row_l = wr * 64 + q * 32 + l31;
      int s_t = (bm & 3) * 128 + row_l + tap - 1;
      bool valid = (unsigned)s_t < 512u;
      int lrow = row_l + tap + 31;
      int base = AOFF + lrow * 32 + ((lrow & 1) << 4);
      #pragma unroll
      for (int p = 0; p < 2; ++p)
        a_addr[tap][q][p] = valid ? (base + p * 6144) : AZ;
    }
  int b_base[2];
  #pragma unroll
  for (int n = 0; n < 2; ++n) {
    int col_l = wc * 64 + n * 32 + l31;
    b_base[n] = col_l * 32 + ((col_l & 1) << 4);
  }

  f32x16 acc[2][2];
  #pragma unroll
  for (int mi = 0; mi < 2; ++mi)
    #pragma unroll
    for (int ni = 0; ni < 2; ++ni) acc[mi][ni] = (f32x16)0.f;

  auto STAGE = [&](int buf, int step) {
    #pragma unroll
    for (int i = 0; i < 9; ++i)
      __builtin_amdgcn_global_load_lds(
        (const __attribute__((address_space(1))) void*)(sb[i] + (size_t)step * sstr[i]),
        (__attribute__((address_space(3))) void*)(smem + sdst[i] + buf * sdb[i]),
        16, 0, 0);
  };

  auto COMP = [&](int buf) {
    #pragma unroll
    for (int tap = 0; tap < 3; ++tap) {
      f16x8 av[2][2], bv[2][2];
      #pragma unroll
      for (int p = 0; p < 2; ++p)
        #pragma unroll
        for (int q = 0; q < 2; ++q) {
          av[p][q] = *(const f16x8*)(smem + ((a_addr[tap][q][p] ^ hx4) + buf * ABUF));
          bv[p][q] = *(const f16x8*)(smem + (buf * BBUF + p * 12288 + tap * 4096 + (b_base[q] ^ hx4)));
        }
      #pragma unroll
      for (int mi = 0; mi < 2; ++mi)
        #pragma unroll
        for (int ni = 0; ni < 2; ++ni) {
          acc[mi][ni] = __builtin_amdgcn_mfma_f32_32x32x16_f16(av[0][mi], bv[0][ni], acc[mi][ni], 0, 0, 0);
          acc[mi][ni] = __builtin_amdgcn_mfma_f32_32x32x16_f16(av[0][mi], bv[1][ni], acc[mi][ni], 0, 0, 0);
          acc[mi][ni] = __builtin_amdgcn_mfma_f32_32x32x16_f16(av[1][mi], bv[0][ni], acc[mi][ni], 0, 0, 0);
        }
    }
  };

  if (tid < 4) {
    *(float4*)(smem + AZ + tid * 16) = make_float4(0.f, 0.f, 0.f, 0.f);
    *(float4*)(smem + AZ + ABUF + tid * 16) = make_float4(0.f, 0.f, 0.f, 0.f);
  }
  STAGE(0, s0); STAGE(1, s0 + 1);
  __syncthreads();                 // drains vmcnt; zeros + first 2 steps visible

  #pragma unroll
  for (int i = 0; i < NS; ++i) {
    COMP(i & 1);
    BAR();                         // all waves done reading buf i&1
    if (i < NS - 2)       { STAGE(i & 1, s0 + i + 2); VMW9(); }
    else if (i == NS - 2) { VMW0(); }
    BAR();                         // step i+1 landed everywhere
  }

  // epilogue. C/D layout: col=lane&31, row=(reg&3)+8*(reg>>2)+4*(lane>>5)
  if constexpr (RAW) {
    float* C = Craw + (size_t)bz * MM * 256;
    #pragma unroll
    for (int mi = 0; mi < 2; ++mi)
      #pragma unroll
      for (int ni = 0; ni < 2; ++ni) {
        int colg = bn * 128 + wc * 64 + ni * 32 + l31;
        #pragma unroll
        for (int r = 0; r < 16; ++r) {
          int rowl = (r & 3) + 8 * (r >> 2) + 4 * half;
          size_t rowg = (size_t)bm * 128 + wr * 64 + mi * 32 + rowl;
          C[rowg * 256 + colg] = acc[mi][ni][r];
        }
      }
  } else {
    const float* bias = bz ? bias1 : bias0;
    f16* Yh = bz ? Y1h : Y0h;
    f16* Yl = bz ? Y1l : Y0l;
    #pragma unroll
    for (int mi = 0; mi < 2; ++mi)
      #pragma unroll
      for (int ni = 0; ni < 2; ++ni) {
        int colg = bn * 128 + wc * 64 + ni * 32 + l31;
        float bvs = bias[colg];
        int cb = colg >> 4, cc = (colg >> 3) & 1, e = colg & 7;
        #pragma unroll
        for (int r = 0; r < 16; ++r) {
          int rowl = (r & 3) + 8 * (r >> 2) + 4 * half;
          int rowg = bm * 128 + wr * 64 + mi * 32 + rowl;
          float v = fmaxf(acc[mi][ni][r] + bvs, 0.f);
          f16 h = (f16)v;
          f16 l = (f16)(v - (float)h);
          size_t o = ((size_t)cb * MM + rowg) * 16 + ((cc ^ (rowg & 1)) << 3) + e;
          Yh[o] = h;
          Yl[o] = l;
        }
      }
  }
}

// ---------------- weight pack+split, all 6 weights in one launch ----------------
// packed per plane: [bn 2][step 16][tap 3][col 128][slot 2][8], slot = gg^(col&1)
__global__ __launch_bounds__(256) void wsplit6(
    const float* __restrict__ W0, const float* __restrict__ W1,
    const float* __restrict__ W2, const float* __restrict__ W3,
    const float* __restrict__ W4, const float* __restrict__ W5,
    f16* __restrict__ Wt)
{
  int z = blockIdx.y;
  const float* W = z==0?W0 : z==1?W1 : z==2?W2 : z==3?W3 : z==4?W4 : W5;
  f16* Thi = Wt + (size_t)z * 2 * WSZ;
  f16* Tlo = Thi + WSZ;
  int id = blockIdx.x * 256 + threadIdx.x;    // [0, 24576)
  int slot = id & 1, col = (id >> 1) & 127;
  int t3 = id >> 8;
  int tap = t3 % 3, bs = t3 / 3;
  int step = bs & 15, bnn = bs >> 4;
  int gg = slot ^ (col & 1);
  int chan = step * 16 + gg * 8;
  int colg = bnn * 128 + col;
  f16x8 hi, lo;
  #pragma unroll
  for (int e = 0; e < 8; ++e) {
    float w = W[(size_t)(tap * 256 + chan + e) * 256 + colg];
    f16 h = (f16)w;
    hi[e] = h;
    lo[e] = (f16)(w - (float)h);
  }
  *(f16x8*)(Thi + (size_t)id * 8) = hi;
  *(f16x8*)(Tlo + (size_t)id * 8) = lo;
}

// ---------------- split f32 -> hi/lo planes (X' layout) ----------------
__global__ __launch_bounds__(256) void split2(
    const float* __restrict__ X, f16* __restrict__ Hi, f16* __restrict__ Lo)
{
  int id = blockIdx.x * 256 + threadIdx.x;    // [0, MM*32)
  int row = id >> 5, chan = (id & 31) * 8;
  const float* src = X + (size_t)row * 256 + chan;
  float4 v0 = *(const float4*)src;
  float4 v1 = *(const float4*)(src + 4);
  float vv[8] = {v0.x, v0.y, v0.z, v0.w, v1.x, v1.y, v1.z, v1.w};
  f16x8 h, l;
  #pragma unroll
  for (int j = 0; j < 8; ++j) {
    f16 hh = (f16)vv[j];
    h[j] = hh;
    l[j] = (f16)(vv[j] - (float)hh);
  }
  size_t o = xoff(row, chan);
  *(f16x8*)(Hi + o) = h;
  *(f16x8*)(Lo + o) = l;
}

// ---------------- fused LN for dur+pit planes (z picks set) ----------------
__global__ __launch_bounds__(256) void lnF(
    f16* __restrict__ P0h, f16* __restrict__ P0l,
    f16* __restrict__ P1h, f16* __restrict__ P1l,
    const float* __restrict__ g0, const float* __restrict__ be0,
    const float* __restrict__ g1, const float* __restrict__ be1)
{
  int z = blockIdx.y;
  f16* Ph = z ? P1h : P0h;
  f16* Pl = z ? P1l : P0l;
  const float* g  = z ? g1 : g0;
  const float* be = z ? be1 : be0;
  int row  = blockIdx.x * 4 + (threadIdx.x >> 6);
  int lane = threadIdx.x & 63;
  size_t o = xoff(row, lane * 4);
  f16x4 h = *(const f16x4*)(Ph + o);
  f16x4 l = *(const f16x4*)(Pl + o);
  float v[4];
  #pragma unroll
  for (int j = 0; j < 4; ++j) v[j] = (float)h[j] + (float)l[j];
  float s = v[0] + v[1] + v[2] + v[3];
  float q = v[0]*v[0] + v[1]*v[1] + v[2]*v[2] + v[3]*v[3];
  #pragma unroll
  for (int d = 32; d > 0; d >>= 1) { s += __shfl_xor(s, d); q += __shfl_xor(q, d); }
  float mean = s * (1.f / 256.f);
  float var  = q * (1.f / 256.f) - mean * mean;
  float inv  = 1.0f / sqrtf(var + 1e-5f);
  float4 gg = *(const float4*)(g + lane * 4);
  float4 bb = *(const float4*)(be + lane * 4);
  float gv[4] = {gg.x, gg.y, gg.z, gg.w};
  float bv[4] = {bb.x, bb.y, bb.z, bb.w};
  #pragma unroll
  for (int j = 0; j < 4; ++j) {
    float oo = (v[j] - mean) * inv * gv[j] + bv[j];
    f16 hh = (f16)oo;
    h[j] = hh;
    l[j] = (f16)(oo - (float)hh);
  }
  *(f16x4*)(Ph + o) = h;
  *(f16x4*)(Pl + o) = l;
}

// ------- fused LN+head for dur (z=0) and pit (z=1, + bucket + emb add) -------
__global__ __launch_bounds__(256) void lnheadD(
    const f16* __restrict__ U0h, const f16* __restrict__ U0l,
    const f16* __restrict__ U1h, const f16* __restrict__ U1l,
    const float* __restrict__ g0, const float* __restrict__ be0,
    const float* __restrict__ wl0, const float* __restrict__ bl0,
    const float* __restrict__ g1, const float* __restrict__ be1,
    const float* __restrict__ wl1, const float* __restrict__ bl1,
    const unsigned char* __restrict__ mask, const float* __restrict__ pc,
    float* __restrict__ o_ldur, float* __restrict__ pred_d,
    float* __restrict__ o_pit,
    const float* __restrict__ pbins, const float* __restrict__ pemb,
    const f16* __restrict__ XPh, const f16* __restrict__ XPl,
    f16* __restrict__ X1h, f16* __restrict__ X1l)
{
  int z = blockIdx.y;
  int row  = blockIdx.x * 4 + (threadIdx.x >> 6);
  int lane = threadIdx.x & 63;
  size_t o = xoff(row, lane * 4);
  const f16* Uh = z ? U1h : U0h;
  const f16* Ul = z ? U1l : U0l;
  f16x4 h = *(const f16x4*)(Uh + o);
  f16x4 l = *(const f16x4*)(Ul + o);
  float v[4];
  #pragma unroll
  for (int j = 0; j < 4; ++j) v[j] = (float)h[j] + (float)l[j];
  float s = v[0] + v[1] + v[2] + v[3];
  float q = v[0]*v[0] + v[1]*v[1] + v[2]*v[2] + v[3]*v[3];
  #pragma unroll
  for (int d = 32; d > 0; d >>= 1) { s += __shfl_xor(s, d); q += __shfl_xor(q, d); }
  float mean = s * (1.f / 256.f);
  float var  = q * (1.f / 256.f) - mean * mean;
  float inv  = 1.0f / sqrtf(var + 1e-5f);
  const float* g  = z ? g1  : g0;
  const float* be = z ? be1 : be0;
  const float* wl = z ? wl1 : wl0;
  float4 gg = *(const float4*)(g + lane * 4);
  float4 bb = *(const float4*)(be + lane * 4);
  float4 ww = *(const float4*)(wl + lane * 4);
  float gv[4] = {gg.x, gg.y, gg.z, gg.w};
  float bv[4] = {bb.x, bb.y, bb.z, bb.w};
  float wv[4] = {ww.x, ww.y, ww.z, ww.w};
  float acc = 0.f;
  #pragma unroll
  for (int j = 0; j < 4; ++j)
    acc += ((v[j] - mean) * inv * gv[j] + bv[j]) * wv[j];
  #pragma unroll
  for (int d = 32; d > 0; d >>= 1) acc += __shfl_xor(acc, d);
  float r = acc + (z ? bl1 : bl0)[0];
  if (mask[row]) r = 0.f;
  if (z == 0) {
    if (lane == 0) { o_ldur[row] = r; pred_d[row] = r; }
  } else {
    r *= pc[0];
    if (lane == 0) o_pit[row] = r;
    int lo = 0, hi = 255;
    while (lo < hi) { int mid = (lo + hi) >> 1; if (pbins[mid] < r) lo = mid + 1; else hi = mid; }
    f16x4 xh = *(const f16x4*)(XPh + o);
    f16x4 xl = *(const f16x4*)(XPl + o);
    float4 e = *(const float4*)(pemb + (size_t)lo * HH + lane * 4);
    float ev[4] = {e.x, e.y, e.z, e.w};
    #pragma unroll
    for (int j = 0; j < 4; ++j) {
      float oo = (float)xh[j] + (float)xl[j] + ev[j];
      f16 hh = (f16)oo;
      xh[j] = hh;
      xl[j] = (f16)(oo - (float)hh);
    }
    *(f16x4*)(X1h + o) = xh;
    *(f16x4*)(X1l + o) = xl;
  }
}

// ------- energy: sum split-K partials + bias + relu + LN -> planes -------
__global__ __launch_bounds__(256) void lnS(
    const float* __restrict__ C0, const float* __restrict__ C1,
    const float* __restrict__ bias,
    const float* __restrict__ g, const float* __restrict__ be,
    f16* __restrict__ Yh, f16* __restrict__ Yl)
{
  int row  = blockIdx.x * 4 + (threadIdx.x >> 6);
  int lane = threadIdx.x & 63;
  size_t ci = (size_t)row * 256 + lane * 4;
  float4 a = *(const float4*)(C0 + ci);
  float4 b = *(const float4*)(C1 + ci);
  float4 bs = *(const float4*)(bias + lane * 4);
  float v[4] = {fmaxf(a.x + b.x + bs.x, 0.f), fmaxf(a.y + b.y + bs.y, 0.f),
                fmaxf(a.z + b.z + bs.z, 0.f), fmaxf(a.w + b.w + bs.w, 0.f)};
  float s = v[0] + v[1] + v[2] + v[3];
  float q = v[0]*v[0] + v[1]*v[1] + v[2]*v[2] + v[3]*v[3];
  #pragma unroll
  for (int d = 32; d > 0; d >>= 1) { s += __shfl_xor(s, d); q += __shfl_xor(q, d); }
  float mean = s * (1.f / 256.f);
  float var  = q * (1.f / 256.f) - mean * mean;
  float inv  = 1.0f / sqrtf(var + 1e-5f);
  float4 gg = *(const float4*)(g + lane * 4);
  float4 bb = *(const float4*)(be + lane * 4);
  float gv[4] = {gg.x, gg.y, gg.z, gg.w};
  float bv[4] = {bb.x, bb.y, bb.z, bb.w};
  f16x4 h, l;
  #pragma unroll
  for (int j = 0; j < 4; ++j) {
    float oo = (v[j] - mean) * inv * gv[j] + bv[j];
    f16 hh = (f16)oo;
    h[j] = hh;
    l[j] = (f16)(oo - (float)hh);
  }
  size_t o = xoff(row, lane * 4);
  *(f16x4*)(Yh + o) = h;
  *(f16x4*)(Yl + o) = l;
}

// ------- energy final: sum partials + bias + relu + LN + head + bucket -------
__global__ __launch_bounds__(256) void lnheadS(
    const float* __restrict__ C0, const float* __restrict__ C1,
    const float* __restrict__ bias,
    const float* __restrict__ g, const float* __restrict__ be,
    const float* __restrict__ wl, const float* __restrict__ bl,
    const unsigned char* __restrict__ mask, const float* __restrict__ ec,
    float* __restrict__ o_ene,
    const float* __restrict__ ebins, const float* __restrict__ eemb,
    const f16* __restrict__ X1h, const f16* __restrict__ X1l,
    f16* __restrict__ X2h, f16* __restrict__ X2l)
{
  int row  = blockIdx.x * 4 + (threadIdx.x >> 6);
  int lane = threadIdx.x & 63;
  size_t ci = (size_t)row * 256 + lane * 4;
  float4 a = *(const float4*)(C0 + ci);
  float4 b = *(const float4*)(C1 + ci);
  float4 bs = *(const float4*)(bias + lane * 4);
  float v[4] = {fmaxf(a.x + b.x + bs.x, 0.f), fmaxf(a.y + b.y + bs.y, 0.f),
                fmaxf(a.z + b.z + bs.z, 0.f), fmaxf(a.w + b.w + bs.w, 0.f)};
  float s = v[0] + v[1] + v[2] + v[3];
  float q = v[0]*v[0] + v[1]*v[1] + v[2]*v[2] + v[3]*v[3];
  #pragma unroll
  for (int d = 32; d > 0; d >>= 1) { s += __shfl_xor(s, d); q += __shfl_xor(q, d); }
  float mean = s * (1.f / 256.f);
  float var  = q * (1.f / 256.f) - mean * mean;
  float inv  = 1.0f / sqrtf(var + 1e-5f);
  float4 gg = *(const float4*)(g + lane * 4);
  float4 bb = *(const float4*)(be + lane * 4);
  float4 ww = *(const float4*)(wl + lane * 4);
  float gv[4] = {gg.x, gg.y, gg.z, gg.w};
  float bv[4] = {bb.x, bb.y, bb.z, bb.w};
  float wv[4] = {ww.x, ww.y, ww.z, ww.w};
  float acc = 0.f;
  #pragma unroll
  for (int j = 0; j < 4; ++j)
    acc += ((v[j] - mean) * inv * gv[j] + bv[j]) * wv[j];
  #pragma unroll
  for (int d = 32; d > 0; d >>= 1) acc += __shfl_xor(acc, d);
  float r = acc + bl[0];
  if (mask[row]) r = 0.f;
  r *= ec[0];
  if (lane == 0) o_ene[row] = r;
  int lo = 0, hi = 255;
  while (lo < hi) { int mid = (lo + hi) >> 1; if (ebins[mid] < r) lo = mid + 1; else hi = mid; }
  size_t o = xoff(row, lane * 4);
  f16x4 xh = *(const f16x4*)(X1h + o);
  f16x4 xl = *(const f16x4*)(X1l + o);
  float4 e = *(const float4*)(eemb + (size_t)lo * HH + lane * 4);
  float ev[4] = {e.x, e.y, e.z, e.w};
  #pragma unroll
  for (int j = 0; j < 4; ++j) {
    float oo = (float)xh[j] + (float)xl[j] + ev[j];
    f16 hh = (f16)oo;
    xh[j] = hh;
    xl[j] = (f16)(oo - (float)hh);
  }
  *(f16x4*)(X2h + o) = xh;
  *(f16x4*)(X2l + o) = xl;
}

// ---------------- duration post: dur, cumsum, mel_len ----------------
__global__ __launch_bounds__(512) void dur_post(
    const float* __restrict__ logdur, const float* __restrict__ dc,
    float* __restrict__ out_dur, float* __restrict__ out_mel_len,
    int* __restrict__ cum_ws, int* __restrict__ mel_len_ws)
{
  __shared__ int wsum[8];
  int b = blockIdx.x, t = threadIdx.x;
  float ld = logdur[b * SS + t];
  float d  = fmaxf(rintf(expf(ld) - 1.f) * dc[0], 0.f);
  out_dur[b * SS + t] = d;
  int di = (int)d;
  int lane = t & 63, w = t >> 6;
  int x = di;
  #pragma unroll
  for (int dd = 1; dd < 64; dd <<= 1) {
    int n = __shfl_up(x, dd);
    if (lane >= dd) x += n;
  }
  if (lane == 63) wsum[w] = x;
  __syncthreads();
  int off = 0;
  for (int i = 0; i < w; ++i) off += wsum[i];
  x += off;
  cum_ws[b * SS + t] = x;
  if (t == SS - 1) {
    int ml = min(x, MAXMEL);
    mel_len_ws[b] = ml;
    out_mel_len[b] = (float)ml;
  }
}

// ---------------- length regulator from X' planes ----------------
__global__ __launch_bounds__(256) void gather_planes(
    const f16* __restrict__ Xhi, const f16* __restrict__ Xlo,
    const int* __restrict__ cum, const int* __restrict__ mel_len_ws,
    float* __restrict__ out_x, float* __restrict__ out_mask)
{
  __shared__ int c[SS];
  int b   = blockIdx.y;
  int tid = threadIdx.x;
  c[tid]       = cum[b * SS + tid];
  c[tid + 256] = cum[b * SS + tid + 256];
  __syncthreads();
  int w = tid >> 6, lane = tid & 63;
  int t = blockIdx.x * 4 + w;
  int lo = 0, hi = SS;
  while (lo < hi) { int mid = (lo + hi) >> 1; if (c[mid] <= t) lo = mid + 1; else hi = mid; }
  int idx = min(lo, SS - 1);
  int ml  = mel_len_ws[b];
  bool m  = (t >= ml);
  float4 v = make_float4(0.f, 0.f, 0.f, 0.f);
  if (!m) {
    size_t o = xoff(b * SS + idx, lane * 4);
    f16x4 xh = *(const f16x4*)(Xhi + o);
    f16x4 xl = *(const f16x4*)(Xlo + o);
    v.x = (float)xh[0] + (float)xl[0];
    v.y = (float)xh[1] + (float)xl[1];
    v.z = (float)xh[2] + (float)xl[2];
    v.w = (float)xh[3] + (float)xl[3];
  }
  *(float4*)(out_x + ((size_t)b * MAXMEL + t) * HH + lane * 4) = v;
  if (lane == 0) out_mask[b * MAXMEL + t] = m ? 1.f : 0.f;
}

// ---------------- launcher ----------------
extern "C" void kernel_launch(void* const* d_in, const int* in_sizes, int n_in,
                              void* d_out, int out_size, void* d_ws, size_t ws_size,
                              hipStream_t stream) {
  const float* x     = (const float*)d_in[0];
  const unsigned char* smask = (const unsigned char*)d_in[1];
  const float* pc    = (const float*)d_in[2];
  const float* ec    = (const float*)d_in[3];
  const float* dc    = (const float*)d_in[4];
  const float* pbins = (const float*)d_in[5];
  const float* ebins = (const float*)d_in[6];
  const float* pemb  = (const float*)d_in[7];
  const float* eemb  = (const float*)d_in[8];

  float* out = (float*)d_out;
  float* o_xexp  = out;
  float* o_pit   = out + (size_t)16777216;
  float* o_ene   = o_pit + 16384;
  float* o_ldur  = o_ene + 16384;
  float* o_dur   = o_ldur + 16384;
  float* o_mlen  = o_dur + 16384;
  float* o_mmask = o_mlen + 32;

  const size_t PL = (size_t)MM * HH;       // f16 elements per plane
  f16* p = (f16*)d_ws;
  f16 *XPh = p, *XPl = p + PL;
  f16 *Tdh = p + 2*PL, *Tdl = p + 3*PL;
  f16 *Tph = p + 4*PL, *Tpl = p + 5*PL;
  f16 *Udh = p + 6*PL, *Udl = p + 7*PL;
  f16 *Uph = p + 8*PL, *Upl = p + 9*PL;
  f16 *X1h = p + 10*PL, *X1l = p + 11*PL;
  f16 *Teh = p + 12*PL, *Tel = p + 13*PL;
  f16 *X2h = p + 14*PL, *X2l = p + 15*PL;
  f16* Wt  = p + 16*PL;                    // 12 planes of WSZ
  float* C0 = (float*)(Wt + 12 * WSZ);     // 2 x MM*256 f32
  float* C1 = C0 + (size_t)MM * 256;
  float* pred_d = C1 + (size_t)MM * 256;
  int*   cum = (int*)(pred_d + MM);
  int*   mlw = cum + MM;

  #define WPH(i) (Wt + (size_t)(i) * 2 * WSZ)
  #define WPL(i) (Wt + (size_t)(i) * 2 * WSZ + WSZ)

  // weights: 0=dur w1(9), 1=dur w2(13), 2=pit w1(19), 3=pit w2(23), 4=ene w1(29), 5=ene w2(33)
  wsplit6<<<dim3(96, 6), 256, 0, stream>>>(
      (const float*)d_in[9], (const float*)d_in[13], (const float*)d_in[19],
      (const float*)d_in[23], (const float*)d_in[29], (const float*)d_in[33], Wt);

  split2<<<2048, 256, 0, stream>>>(x, XPh, XPl);

  dim3 cgrid(128, 2, 2);
  dim3 rgrid(MM / 4);
  dim3 rgrid2(MM / 4, 2);

  // fused dur+pit conv1
  conv16<16, 0><<<cgrid, 256, 0, stream>>>(
      XPh, XPl, XPh, XPl,
      WPH(0), WPL(0), WPH(2), WPL(2),
      (const float*)d_in[10], (const float*)d_in[20],
      Tdh, Tdl, Tph, Tpl, nullptr);
  lnF<<<rgrid2, 256, 0, stream>>>(Tdh, Tdl, Tph, Tpl,
      (const float*)d_in[11], (const float*)d_in[12],
      (const float*)d_in[21], (const float*)d_in[22]);
  // fused dur+pit conv2
  conv16<16, 0><<<cgrid, 256, 0, stream>>>(
      Tdh, Tdl, Tph, Tpl,
      WPH(1), WPL(1), WPH(3), WPL(3),
      (const float*)d_in[14], (const float*)d_in[24],
      Udh, Udl, Uph, Upl, nullptr);
  lnheadD<<<rgrid2, 256, 0, stream>>>(
      Udh, Udl, Uph, Upl,
      (const float*)d_in[15], (const float*)d_in[16],
      (const float*)d_in[17], (const float*)d_in[18],
      (const float*)d_in[25], (const float*)d_in[26],
      (const float*)d_in[27], (const float*)d_in[28],
      smask, pc, o_ldur, pred_d, o_pit, pbins, pemb,
      XPh, XPl, X1h, X1l);
  dur_post<<<BB, 512, 0, stream>>>(pred_d, dc, o_dur, o_mlen, cum, mlw);

  // energy conv1 (split-K) + LN
  conv16<8, 1><<<cgrid, 256, 0, stream>>>(
      X1h, X1l, X1h, X1l,
      WPH(4), WPL(4), WPH(4), WPL(4),
      nullptr, nullptr, nullptr, nullptr, nullptr, nullptr, C0);
  lnS<<<rgrid, 256, 0, stream>>>(C0, C1, (const float*)d_in[30],
      (const float*)d_in[31], (const float*)d_in[32], Teh, Tel);
  // energy conv2 (split-K) + LN+head+bucket
  conv16<8, 1><<<cgrid, 256, 0, stream>>>(
      Teh, Tel, Teh, Tel,
      WPH(5), WPL(5), WPH(5), WPL(5),
      nullptr, nullptr, nullptr, nullptr, nullptr, nullptr, C0);
  lnheadS<<<rgrid, 256, 0, stream>>>(C0, C1, (const float*)d_in[34],
      (const float*)d_in[35], (const float*)d_in[36],
      (const float*)d_in[37], (const float*)d_in[38],
      smask, ec, o_ene, ebins, eemb, X1h, X1l, X2h, X2l);

  dim3 ggrid(MAXMEL / 4, BB);
  gather_planes<<<ggrid, 256, 0, stream>>>(X2h, X2l, cum, mlw, o_xexp, o_mmask);

  #undef WPH
  #undef WPL
}